// Round 1
// baseline (1200.494 us; speedup 1.0000x reference)
//
#include <hip/hip_runtime.h>
#include <math.h>

#define SEQ 2048
#define DIMD 1024
#define NH 16
#define HDIM 64
#define NBATCH 2

#define MODE_Q 0
#define MODE_K 1
#define MODE_V 2
#define MODE_O 3

// ---------------------------------------------------------------------------
// RoPE table: sin/cos of t * 10000^(-2i/64), t in [0,2048), i in [0,32)
// ---------------------------------------------------------------------------
__global__ void rope_table_kernel(float* __restrict__ sintab,
                                  float* __restrict__ costab) {
  int idx = blockIdx.x * 256 + threadIdx.x;  // 65536 total
  int t = idx >> 5;
  int i = idx & 31;
  float inv = powf(10000.0f, -(float)(2 * i) * (1.0f / 64.0f));
  float a = (float)t * inv;
  sintab[idx] = sinf(a);
  costab[idx] = cosf(a);
}

// ---------------------------------------------------------------------------
// f32 NT GEMM: C[m,n] = dot(A[m,:1024], W[n,:1024]) + bias[n], fused epilogue.
// Tile 128x128, BK=16, 256 threads, 8x8 per thread (as 2x2 chunks of 4x4).
// LDS stored k-major As[k][m] so compute reads are contiguous float4.
// ---------------------------------------------------------------------------
template <int MODE>
__global__ __launch_bounds__(256) void gemm_kernel(
    const float* __restrict__ A, const float* __restrict__ W,
    const float* __restrict__ bias, float* __restrict__ out0,
    float* __restrict__ out1, const float* __restrict__ sintab,
    const float* __restrict__ costab) {
  __shared__ float As[16][132];
  __shared__ float Bs[16][132];
  const int t = threadIdx.x;
  const int tx = t & 15;
  const int ty = t >> 4;
  const int m0 = blockIdx.y * 128;
  const int n0 = blockIdx.x * 128;

  float acc[8][8];
#pragma unroll
  for (int i = 0; i < 8; ++i)
#pragma unroll
    for (int j = 0; j < 8; ++j) acc[i][j] = 0.0f;

  const int arow = t >> 2;  // 0..63
  const int ak4 = t & 3;    // float4 index within 16-wide k chunk
  const float* Ap = A + (size_t)(m0 + arow) * DIMD + ak4 * 4;
  const float* Wp = W + (size_t)(n0 + arow) * DIMD + ak4 * 4;

  for (int k0 = 0; k0 < DIMD; k0 += 16) {
    float4 a0 = *(const float4*)(Ap + k0);
    float4 a1 = *(const float4*)(Ap + (size_t)64 * DIMD + k0);
    float4 b0 = *(const float4*)(Wp + k0);
    float4 b1 = *(const float4*)(Wp + (size_t)64 * DIMD + k0);
    __syncthreads();
    As[ak4 * 4 + 0][arow] = a0.x;
    As[ak4 * 4 + 1][arow] = a0.y;
    As[ak4 * 4 + 2][arow] = a0.z;
    As[ak4 * 4 + 3][arow] = a0.w;
    As[ak4 * 4 + 0][arow + 64] = a1.x;
    As[ak4 * 4 + 1][arow + 64] = a1.y;
    As[ak4 * 4 + 2][arow + 64] = a1.z;
    As[ak4 * 4 + 3][arow + 64] = a1.w;
    Bs[ak4 * 4 + 0][arow] = b0.x;
    Bs[ak4 * 4 + 1][arow] = b0.y;
    Bs[ak4 * 4 + 2][arow] = b0.z;
    Bs[ak4 * 4 + 3][arow] = b0.w;
    Bs[ak4 * 4 + 0][arow + 64] = b1.x;
    Bs[ak4 * 4 + 1][arow + 64] = b1.y;
    Bs[ak4 * 4 + 2][arow + 64] = b1.z;
    Bs[ak4 * 4 + 3][arow + 64] = b1.w;
    __syncthreads();
#pragma unroll
    for (int kk = 0; kk < 16; ++kk) {
      float av[8], bv[8];
      *(float4*)&av[0] = *(const float4*)&As[kk][ty * 4];
      *(float4*)&av[4] = *(const float4*)&As[kk][64 + ty * 4];
      *(float4*)&bv[0] = *(const float4*)&Bs[kk][tx * 4];
      *(float4*)&bv[4] = *(const float4*)&Bs[kk][64 + tx * 4];
#pragma unroll
      for (int i = 0; i < 8; ++i)
#pragma unroll
        for (int j = 0; j < 8; ++j) acc[i][j] = fmaf(av[i], bv[j], acc[i][j]);
    }
  }

  // Epilogue: per row (8) x per 4-wide col chunk (2)
#pragma unroll
  for (int i = 0; i < 8; ++i) {
    int m = m0 + ((i < 4) ? (ty * 4 + i) : (64 + ty * 4 + (i - 4)));
    int b = m >> 11;
    int s = m & 2047;
#pragma unroll
    for (int c = 0; c < 2; ++c) {
      int nb = n0 + c * 64 + tx * 4;  // 4-aligned global col base
      float4 bv4 = *(const float4*)&bias[nb];
      float4 v;
      v.x = acc[i][c * 4 + 0] + bv4.x;
      v.y = acc[i][c * 4 + 1] + bv4.y;
      v.z = acc[i][c * 4 + 2] + bv4.z;
      v.w = acc[i][c * 4 + 3] + bv4.w;

      if (MODE == MODE_O) {
        *(float4*)&out0[(size_t)m * DIMD + nb] = v;
      } else if (MODE == MODE_V) {
        int h = nb >> 6;
        int d0 = nb & 63;
        *(float4*)&out0[(((size_t)b * NH + h) * SEQ + s) * HDIM + d0] = v;
      } else if (MODE == MODE_K) {
        int h = nb >> 6;
        int d0 = nb & 63;
        int pidx = s * 32 + (d0 >> 1);
        float2 sn = *(const float2*)&sintab[pidx];
        float2 cs = *(const float2*)&costab[pidx];
        float4 r;
        r.x = v.x * cs.x - v.y * sn.x;
        r.y = v.x * sn.x + v.y * cs.x;
        r.z = v.z * cs.y - v.w * sn.y;
        r.w = v.z * sn.y + v.w * cs.y;
        *(float4*)&out0[(((size_t)b * NH + h) * SEQ + s) * HDIM + d0] = r;
      } else {  // MODE_Q: chunk 0 = q (rope), chunk 1 = gate (sigmoid)
        int h = nb >> 7;
        if (c == 0) {
          int d0 = tx * 4;
          int pidx = s * 32 + (d0 >> 1);
          float2 sn = *(const float2*)&sintab[pidx];
          float2 cs = *(const float2*)&costab[pidx];
          float4 r;
          r.x = v.x * cs.x - v.y * sn.x;
          r.y = v.x * sn.x + v.y * cs.x;
          r.z = v.z * cs.y - v.w * sn.y;
          r.w = v.z * sn.y + v.w * cs.y;
          *(float4*)&out0[(((size_t)b * NH + h) * SEQ + s) * HDIM + d0] = r;
        } else {
          int g0 = tx * 4;
          float4 r;
          r.x = 1.0f / (1.0f + expf(-v.x));
          r.y = 1.0f / (1.0f + expf(-v.y));
          r.z = 1.0f / (1.0f + expf(-v.z));
          r.w = 1.0f / (1.0f + expf(-v.w));
          *(float4*)&out1[((size_t)b * SEQ + s) * DIMD + h * HDIM + g0] = r;
        }
      }
    }
  }
}

// ---------------------------------------------------------------------------
// f32 flash attention. Grid (S/64, B*H), 256 threads.
// Q tile 64x64 in LDS, K/V tiles 64 cols. P overlays the K buffer (LDS<64KB).
// Thread: 4 rows (rg..rg+3) x 4 cols (jj*16+cq) of scores; 4 rows x 4 dims
// (dd*16+cq) of output. Row reductions via 16-lane shuffles.
// Writes attn * sigmoid(gate) in (B,S,D) layout.
// ---------------------------------------------------------------------------
__global__ __launch_bounds__(256) void flash_kernel(
    const float* __restrict__ qw, const float* __restrict__ kw,
    const float* __restrict__ vw, const float* __restrict__ sg,
    float* __restrict__ ag) {
  __shared__ float Qt[64][68];
  __shared__ float KPt[64][68];  // K tile, then reused for P
  __shared__ float Vt[64][68];   // transposed: Vt[dim][j]
  const int t = threadIdx.x;
  const int bh = blockIdx.y;
  const int q0 = blockIdx.x * 64;
  const size_t base = (size_t)bh * SEQ * HDIM;

#pragma unroll
  for (int r = 0; r < 4; ++r) {
    int id = t + 256 * r;
    int row = id >> 4, d4 = id & 15;
    float4 qv = *(const float4*)&qw[base + (size_t)(q0 + row) * HDIM + d4 * 4];
    *(float4*)&Qt[row][d4 * 4] = qv;
  }

  const int rg = (t >> 4) * 4;  // row group base 0..60
  const int cq = t & 15;
  float m_i[4], l_i[4], o[4][4];
#pragma unroll
  for (int i = 0; i < 4; ++i) {
    m_i[i] = -1e30f;
    l_i[i] = 0.0f;
#pragma unroll
    for (int d = 0; d < 4; ++d) o[i][d] = 0.0f;
  }

  for (int j0 = 0; j0 < SEQ; j0 += 64) {
    __syncthreads();  // prev PV done; also guards initial Qt fill
#pragma unroll
    for (int r = 0; r < 4; ++r) {
      int id = t + 256 * r;
      int row = id >> 4, d4 = id & 15;
      float4 kv = *(const float4*)&kw[base + (size_t)(j0 + row) * HDIM + d4 * 4];
      *(float4*)&KPt[row][d4 * 4] = kv;
      float4 vv = *(const float4*)&vw[base + (size_t)(j0 + row) * HDIM + d4 * 4];
      Vt[d4 * 4 + 0][row] = vv.x;
      Vt[d4 * 4 + 1][row] = vv.y;
      Vt[d4 * 4 + 2][row] = vv.z;
      Vt[d4 * 4 + 3][row] = vv.w;
    }
    __syncthreads();

    float sc[4][4];
#pragma unroll
    for (int i = 0; i < 4; ++i)
#pragma unroll
      for (int j = 0; j < 4; ++j) sc[i][j] = 0.0f;

#pragma unroll
    for (int d4 = 0; d4 < 16; ++d4) {
      float4 q4[4], k4[4];
#pragma unroll
      for (int i = 0; i < 4; ++i) q4[i] = *(const float4*)&Qt[rg + i][d4 * 4];
#pragma unroll
      for (int j = 0; j < 4; ++j)
        k4[j] = *(const float4*)&KPt[j * 16 + cq][d4 * 4];
#pragma unroll
      for (int i = 0; i < 4; ++i)
#pragma unroll
        for (int j = 0; j < 4; ++j) {
          sc[i][j] = fmaf(q4[i].x, k4[j].x, sc[i][j]);
          sc[i][j] = fmaf(q4[i].y, k4[j].y, sc[i][j]);
          sc[i][j] = fmaf(q4[i].z, k4[j].z, sc[i][j]);
          sc[i][j] = fmaf(q4[i].w, k4[j].w, sc[i][j]);
        }
    }

    float p[4][4], fct[4];
#pragma unroll
    for (int i = 0; i < 4; ++i) {
#pragma unroll
      for (int j = 0; j < 4; ++j) sc[i][j] *= 0.125f;
      float mx = fmaxf(fmaxf(sc[i][0], sc[i][1]), fmaxf(sc[i][2], sc[i][3]));
      mx = fmaxf(mx, __shfl_xor(mx, 1));
      mx = fmaxf(mx, __shfl_xor(mx, 2));
      mx = fmaxf(mx, __shfl_xor(mx, 4));
      mx = fmaxf(mx, __shfl_xor(mx, 8));
      float mn = fmaxf(m_i[i], mx);
      float rs = 0.0f;
#pragma unroll
      for (int j = 0; j < 4; ++j) {
        p[i][j] = expf(sc[i][j] - mn);
        rs += p[i][j];
      }
      rs += __shfl_xor(rs, 1);
      rs += __shfl_xor(rs, 2);
      rs += __shfl_xor(rs, 4);
      rs += __shfl_xor(rs, 8);
      float f = expf(m_i[i] - mn);
      l_i[i] = l_i[i] * f + rs;
      m_i[i] = mn;
      fct[i] = f;
    }
    __syncthreads();  // all QK reads of KPt done before P overwrite
#pragma unroll
    for (int i = 0; i < 4; ++i) {
#pragma unroll
      for (int d = 0; d < 4; ++d) o[i][d] *= fct[i];
#pragma unroll
      for (int j = 0; j < 4; ++j) KPt[rg + i][j * 16 + cq] = p[i][j];
    }
    __syncthreads();

#pragma unroll
    for (int j4 = 0; j4 < 16; ++j4) {
      float4 p4[4], v4[4];
#pragma unroll
      for (int i = 0; i < 4; ++i) p4[i] = *(const float4*)&KPt[rg + i][j4 * 4];
#pragma unroll
      for (int d = 0; d < 4; ++d)
        v4[d] = *(const float4*)&Vt[d * 16 + cq][j4 * 4];
#pragma unroll
      for (int i = 0; i < 4; ++i)
#pragma unroll
        for (int d = 0; d < 4; ++d) {
          o[i][d] = fmaf(p4[i].x, v4[d].x, o[i][d]);
          o[i][d] = fmaf(p4[i].y, v4[d].y, o[i][d]);
          o[i][d] = fmaf(p4[i].z, v4[d].z, o[i][d]);
          o[i][d] = fmaf(p4[i].w, v4[d].w, o[i][d]);
        }
    }
  }

  int b = bh >> 4, h = bh & 15;
#pragma unroll
  for (int i = 0; i < 4; ++i) {
    int srow = q0 + rg + i;
    size_t obase = ((size_t)b * SEQ + srow) * DIMD + h * HDIM;
    float inv_l = 1.0f / l_i[i];
#pragma unroll
    for (int d = 0; d < 4; ++d) {
      int dim = d * 16 + cq;
      ag[obase + dim] = o[i][d] * inv_l * sg[obase + dim];
    }
  }
}

// ---------------------------------------------------------------------------
extern "C" void kernel_launch(void* const* d_in, const int* in_sizes, int n_in,
                              void* d_out, int out_size, void* d_ws,
                              size_t ws_size, hipStream_t stream) {
  const float* query = (const float*)d_in[0];
  const float* Wq = (const float*)d_in[1];
  const float* bq = (const float*)d_in[2];
  const float* Wk = (const float*)d_in[3];
  const float* bk = (const float*)d_in[4];
  const float* Wv = (const float*)d_in[5];
  const float* bv = (const float*)d_in[6];
  const float* Wo = (const float*)d_in[7];
  const float* bo = (const float*)d_in[8];
  float* out = (float*)d_out;

  float* ws = (float*)d_ws;
  float* sintab = ws;                // 65536
  float* costab = ws + 65536;        // 65536
  float* qw = ws + 131072;           // (B,H,S,64) 4194304
  float* kw = qw + 4194304;
  float* vw = kw + 4194304;
  float* sg = vw + 4194304;          // (B,S,D) sigmoid(gate)
  float* ag = sg + 4194304;          // (B,S,D) gated attention

  rope_table_kernel<<<256, 256, 0, stream>>>(sintab, costab);
  gemm_kernel<MODE_Q><<<dim3(16, 32), 256, 0, stream>>>(query, Wq, bq, qw, sg,
                                                        sintab, costab);
  gemm_kernel<MODE_K><<<dim3(8, 32), 256, 0, stream>>>(query, Wk, bk, kw,
                                                       nullptr, sintab, costab);
  gemm_kernel<MODE_V><<<dim3(8, 32), 256, 0, stream>>>(query, Wv, bv, vw,
                                                       nullptr, sintab, costab);
  flash_kernel<<<dim3(32, 32), 256, 0, stream>>>(qw, kw, vw, sg, ag);
  gemm_kernel<MODE_O><<<dim3(8, 32), 256, 0, stream>>>(ag, Wo, bo, out, nullptr,
                                                       sintab, costab);
}

// Round 2
// 341.683 us; speedup vs baseline: 3.5135x; 3.5135x over previous
//
#include <hip/hip_runtime.h>
#include <math.h>

#define SEQ 2048
#define DIMD 1024
#define NH 16
#define HDIM 64

#define MODE_Q 0
#define MODE_K 1
#define MODE_V 2
#define MODE_O 3

typedef _Float16 h8 __attribute__((ext_vector_type(8)));
typedef _Float16 h4 __attribute__((ext_vector_type(4)));
typedef float f32x4 __attribute__((ext_vector_type(4)));

// element-index swizzle for [64][64] f16 tiles (128B rows): XOR byte bits 4-6
// with (row&7) -> element bits 3-5.  Breaks the 16-lane same-column conflict.
__device__ __forceinline__ int SWE(int r, int c) {
  return ((r << 6) + c) ^ ((r & 7) << 3);
}

// ---------------------------------------------------------------------------
// RoPE table in double precision (f32 powf cost us ~5e-4 absmax headroom)
// ---------------------------------------------------------------------------
__global__ void rope_table_kernel(float* __restrict__ sintab,
                                  float* __restrict__ costab) {
  int idx = blockIdx.x * 256 + threadIdx.x;  // 65536
  int t = idx >> 5;
  int i = idx & 31;
  double inv = pow(10000.0, -(double)(2 * i) / 64.0);
  double a = (double)t * inv;
  sintab[idx] = (float)sin(a);
  costab[idx] = (float)cos(a);
}

// ---------------------------------------------------------------------------
// f32 -> f16 hi/lo split (hi = f16(x), lo = f16(x - hi)), float4 vectorized
// ---------------------------------------------------------------------------
__global__ void split_kernel(const float* __restrict__ src,
                             _Float16* __restrict__ hi,
                             _Float16* __restrict__ lo, int n4) {
  int i = blockIdx.x * 256 + threadIdx.x;
  if (i >= n4) return;
  float4 v = ((const float4*)src)[i];
  h4 H, L;
  H[0] = (_Float16)v.x; L[0] = (_Float16)(v.x - (float)H[0]);
  H[1] = (_Float16)v.y; L[1] = (_Float16)(v.y - (float)H[1]);
  H[2] = (_Float16)v.z; L[2] = (_Float16)(v.z - (float)H[2]);
  H[3] = (_Float16)v.w; L[3] = (_Float16)(v.w - (float)H[3]);
  ((h4*)hi)[i] = H;
  ((h4*)lo)[i] = L;
}

// ---------------------------------------------------------------------------
// Split-f16 NT GEMM: C[m,n] = dot(A[m,:], W[n,:]) + bias[n], 3 MFMAs per frag
// pair (hh + hl + lh).  Tile 128x128, BK=32, 4 waves of 64x64 (4x4 frags of
// 16x16x32).  LDS rows padded to 40 f16 (80B) -> 2-way bank aliasing (free).
// Fused epilogues: Q->rope(q)+sigmoid(gate), K->rope, V->transposed f16,
// O->f32 out.
// ---------------------------------------------------------------------------
template <int MODE>
__global__ __launch_bounds__(256) void gemm_kernel(
    const _Float16* __restrict__ Ah, const _Float16* __restrict__ Al,
    const _Float16* __restrict__ Wh, const _Float16* __restrict__ Wl,
    const float* __restrict__ bias, _Float16* __restrict__ o16a,
    _Float16* __restrict__ o16b, float* __restrict__ o32,
    const float* __restrict__ sintab, const float* __restrict__ costab) {
  __shared__ _Float16 Ash[128][40];
  __shared__ _Float16 Asl[128][40];
  __shared__ _Float16 Bsh[128][40];
  __shared__ _Float16 Bsl[128][40];
  const int t = threadIdx.x;
  const int lane = t & 63;
  const int w = t >> 6;
  const int wm = w & 1, wn = w >> 1;
  const int fr = lane & 15;
  const int fk = (lane >> 4) * 8;
  const int m0 = blockIdx.y * 128, n0 = blockIdx.x * 128;

  f32x4 acc[4][4];
#pragma unroll
  for (int i = 0; i < 4; ++i)
#pragma unroll
    for (int j = 0; j < 4; ++j) acc[i][j] = (f32x4){0.f, 0.f, 0.f, 0.f};

  const int srow = t >> 1;
  const int sc = (t & 1) * 16;
  const _Float16* pAh = Ah + (size_t)(m0 + srow) * DIMD + sc;
  const _Float16* pAl = Al + (size_t)(m0 + srow) * DIMD + sc;
  const _Float16* pWh = Wh + (size_t)(n0 + srow) * DIMD + sc;
  const _Float16* pWl = Wl + (size_t)(n0 + srow) * DIMD + sc;

  for (int k0 = 0; k0 < DIMD; k0 += 32) {
    h8 rah0 = *(const h8*)(pAh + k0);
    h8 rah1 = *(const h8*)(pAh + k0 + 8);
    h8 ral0 = *(const h8*)(pAl + k0);
    h8 ral1 = *(const h8*)(pAl + k0 + 8);
    h8 rbh0 = *(const h8*)(pWh + k0);
    h8 rbh1 = *(const h8*)(pWh + k0 + 8);
    h8 rbl0 = *(const h8*)(pWl + k0);
    h8 rbl1 = *(const h8*)(pWl + k0 + 8);
    __syncthreads();
    *(h8*)&Ash[srow][sc] = rah0;
    *(h8*)&Ash[srow][sc + 8] = rah1;
    *(h8*)&Asl[srow][sc] = ral0;
    *(h8*)&Asl[srow][sc + 8] = ral1;
    *(h8*)&Bsh[srow][sc] = rbh0;
    *(h8*)&Bsh[srow][sc + 8] = rbh1;
    *(h8*)&Bsl[srow][sc] = rbl0;
    *(h8*)&Bsl[srow][sc + 8] = rbl1;
    __syncthreads();

    h8 ah[4], al[4], bh[4], bl[4];
#pragma unroll
    for (int mi = 0; mi < 4; ++mi) {
      ah[mi] = *(const h8*)&Ash[wm * 64 + mi * 16 + fr][fk];
      al[mi] = *(const h8*)&Asl[wm * 64 + mi * 16 + fr][fk];
    }
#pragma unroll
    for (int ni = 0; ni < 4; ++ni) {
      bh[ni] = *(const h8*)&Bsh[wn * 64 + ni * 16 + fr][fk];
      bl[ni] = *(const h8*)&Bsl[wn * 64 + ni * 16 + fr][fk];
    }
#pragma unroll
    for (int mi = 0; mi < 4; ++mi)
#pragma unroll
      for (int ni = 0; ni < 4; ++ni) {
        acc[mi][ni] = __builtin_amdgcn_mfma_f32_16x16x32_f16(
            ah[mi], bh[ni], acc[mi][ni], 0, 0, 0);
        acc[mi][ni] = __builtin_amdgcn_mfma_f32_16x16x32_f16(
            ah[mi], bl[ni], acc[mi][ni], 0, 0, 0);
        acc[mi][ni] = __builtin_amdgcn_mfma_f32_16x16x32_f16(
            al[mi], bh[ni], acc[mi][ni], 0, 0, 0);
      }
  }

  // Epilogue. C/D layout: col = lane&15, row = (lane>>4)*4 + reg.
#pragma unroll
  for (int mi = 0; mi < 4; ++mi)
#pragma unroll
    for (int ni = 0; ni < 4; ++ni) {
      const int col = n0 + wn * 64 + ni * 16 + fr;
      const float bsv = bias[col];
#pragma unroll
      for (int r = 0; r < 4; ++r) {
        const int row = m0 + wm * 64 + mi * 16 + (lane >> 4) * 4 + r;
        float v = acc[mi][ni][r] + bsv;
        const int b = row >> 11;
        const int s = row & (SEQ - 1);
        if (MODE == MODE_O) {
          o32[(size_t)row * DIMD + col] = v;
        } else if (MODE == MODE_V) {
          const int h = col >> 6, d = col & 63;
          o16a[((size_t)(b * NH + h) * HDIM + d) * SEQ + s] = (_Float16)v;
        } else if (MODE == MODE_K) {
          const int h = col >> 6, d = col & 63;
          float vp = __shfl_xor(v, 1);
          const int pi = s * 32 + (d >> 1);
          float sn = sintab[pi], cs = costab[pi];
          float rv = (d & 1) ? (vp * sn + v * cs) : (v * cs - vp * sn);
          o16a[((size_t)(b * NH + h) * SEQ + s) * HDIM + d] = (_Float16)rv;
        } else {  // MODE_Q
          const int h = n0 >> 7;
          const int d = col & 63;
          if (wn == 0) {  // q half: rope
            float vp = __shfl_xor(v, 1);
            const int pi = s * 32 + (d >> 1);
            float sn = sintab[pi], cs = costab[pi];
            float rv = (d & 1) ? (vp * sn + v * cs) : (v * cs - vp * sn);
            o16a[((size_t)(b * NH + h) * SEQ + s) * HDIM + d] = (_Float16)rv;
          } else {  // gate half: sigmoid -> (B,S,D)
            float g = 1.0f / (1.0f + __expf(-v));
            o16b[((size_t)(b * SEQ + s)) * DIMD + h * HDIM + d] = (_Float16)g;
          }
        }
      }
    }
}

// ---------------------------------------------------------------------------
// f16 MFMA flash attention. Grid (S/64, B*H), 256 thr = 4 waves.
// Wave w owns q-rows 16w..16w+15.  Q a-frags in registers for all tiles.
// K[64][64] and Vt[64][64] staged swizzled; P through swizzled LDS.
// Online softmax per lane over its 4 C-rows via 16-lane shfl reductions.
// Epilogue: o/l * sigmoid_gate, written as f16 hi/lo split for out-proj.
// ---------------------------------------------------------------------------
__global__ __launch_bounds__(256) void flash_kernel(
    const _Float16* __restrict__ qh, const _Float16* __restrict__ kh,
    const _Float16* __restrict__ vt, const _Float16* __restrict__ sg,
    _Float16* __restrict__ agh, _Float16* __restrict__ agl) {
  __shared__ _Float16 K_lds[4096];
  __shared__ _Float16 Vt_lds[4096];
  __shared__ _Float16 P_lds[4096];
  const int t = threadIdx.x;
  const int lane = t & 63;
  const int w = t >> 6;
  const int fr = lane & 15;
  const int fk = (lane >> 4) * 8;
  const int bh = blockIdx.y;
  const int q0 = blockIdx.x * 64;
  const size_t kvbase = (size_t)bh * (SEQ * HDIM);

  h8 aq[2];
  {
    const _Float16* qp = qh + kvbase + (size_t)(q0 + 16 * w + fr) * HDIM + fk;
    aq[0] = *(const h8*)(qp);
    aq[1] = *(const h8*)(qp + 32);
  }

  f32x4 oacc[4];
  float m_i[4], l_i[4];
#pragma unroll
  for (int i = 0; i < 4; ++i) {
    oacc[i] = (f32x4){0.f, 0.f, 0.f, 0.f};
    m_i[i] = -1e30f;
    l_i[i] = 0.f;
  }

  const int srow = t >> 2;          // 0..63
  const int scb = (t & 3) * 16;     // 0,16,32,48
  const _Float16* kp = kh + kvbase + (size_t)srow * HDIM + scb;
  const _Float16* vp = vt + kvbase + (size_t)srow * SEQ + scb;

  for (int j0 = 0; j0 < SEQ; j0 += 64) {
    h8 k0v = *(const h8*)(kp + (size_t)j0 * HDIM);
    h8 k1v = *(const h8*)(kp + (size_t)j0 * HDIM + 8);
    h8 v0v = *(const h8*)(vp + j0);
    h8 v1v = *(const h8*)(vp + j0 + 8);
    __syncthreads();  // previous tile's K/Vt reads complete
    *(h8*)&K_lds[SWE(srow, scb)] = k0v;
    *(h8*)&K_lds[SWE(srow, scb + 8)] = k1v;
    *(h8*)&Vt_lds[SWE(srow, scb)] = v0v;
    *(h8*)&Vt_lds[SWE(srow, scb + 8)] = v1v;
    __syncthreads();

    // S = Q K^T
    f32x4 sacc[4];
#pragma unroll
    for (int nf = 0; nf < 4; ++nf) sacc[nf] = (f32x4){0.f, 0.f, 0.f, 0.f};
#pragma unroll
    for (int nf = 0; nf < 4; ++nf) {
      h8 kb0 = *(const h8*)&K_lds[SWE(16 * nf + fr, fk)];
      h8 kb1 = *(const h8*)&K_lds[SWE(16 * nf + fr, fk + 32)];
      sacc[nf] =
          __builtin_amdgcn_mfma_f32_16x16x32_f16(aq[0], kb0, sacc[nf], 0, 0, 0);
      sacc[nf] =
          __builtin_amdgcn_mfma_f32_16x16x32_f16(aq[1], kb1, sacc[nf], 0, 0, 0);
    }

    // online softmax on 4 rows per lane
    float fct[4];
#pragma unroll
    for (int r = 0; r < 4; ++r) {
      float s0 = sacc[0][r] * 0.125f;
      float s1 = sacc[1][r] * 0.125f;
      float s2 = sacc[2][r] * 0.125f;
      float s3 = sacc[3][r] * 0.125f;
      float mx = fmaxf(fmaxf(s0, s1), fmaxf(s2, s3));
      mx = fmaxf(mx, __shfl_xor(mx, 1));
      mx = fmaxf(mx, __shfl_xor(mx, 2));
      mx = fmaxf(mx, __shfl_xor(mx, 4));
      mx = fmaxf(mx, __shfl_xor(mx, 8));
      float mn = fmaxf(m_i[r], mx);
      float p0 = __expf(s0 - mn);
      float p1 = __expf(s1 - mn);
      float p2 = __expf(s2 - mn);
      float p3 = __expf(s3 - mn);
      float rs = p0 + p1 + p2 + p3;
      rs += __shfl_xor(rs, 1);
      rs += __shfl_xor(rs, 2);
      rs += __shfl_xor(rs, 4);
      rs += __shfl_xor(rs, 8);
      float f = __expf(m_i[r] - mn);
      l_i[r] = l_i[r] * f + rs;
      m_i[r] = mn;
      fct[r] = f;
      const int prow = 16 * w + (lane >> 4) * 4 + r;
      P_lds[SWE(prow, fr)] = (_Float16)p0;
      P_lds[SWE(prow, 16 + fr)] = (_Float16)p1;
      P_lds[SWE(prow, 32 + fr)] = (_Float16)p2;
      P_lds[SWE(prow, 48 + fr)] = (_Float16)p3;
    }
#pragma unroll
    for (int df = 0; df < 4; ++df)
#pragma unroll
      for (int r = 0; r < 4; ++r) oacc[df][r] *= fct[r];

    __syncthreads();  // make own-wave P writes visible (cross-lane)

    // O += P V
    h8 pa0 = *(const h8*)&P_lds[SWE(16 * w + fr, fk)];
    h8 pa1 = *(const h8*)&P_lds[SWE(16 * w + fr, fk + 32)];
#pragma unroll
    for (int df = 0; df < 4; ++df) {
      h8 vb0 = *(const h8*)&Vt_lds[SWE(16 * df + fr, fk)];
      h8 vb1 = *(const h8*)&Vt_lds[SWE(16 * df + fr, fk + 32)];
      oacc[df] =
          __builtin_amdgcn_mfma_f32_16x16x32_f16(pa0, vb0, oacc[df], 0, 0, 0);
      oacc[df] =
          __builtin_amdgcn_mfma_f32_16x16x32_f16(pa1, vb1, oacc[df], 0, 0, 0);
    }
  }

  const int b = bh >> 4, h = bh & 15;
#pragma unroll
  for (int r = 0; r < 4; ++r) {
    const int qrow = q0 + 16 * w + (lane >> 4) * 4 + r;
    const float inv = 1.0f / l_i[r];
    const size_t obase = ((size_t)(b * SEQ + qrow)) * DIMD + h * HDIM;
#pragma unroll
    for (int df = 0; df < 4; ++df) {
      const int d = df * 16 + fr;
      float val = oacc[df][r] * inv * (float)sg[obase + d];
      _Float16 hi = (_Float16)val;
      agh[obase + d] = hi;
      agl[obase + d] = (_Float16)(val - (float)hi);
    }
  }
}

// ---------------------------------------------------------------------------
extern "C" void kernel_launch(void* const* d_in, const int* in_sizes, int n_in,
                              void* d_out, int out_size, void* d_ws,
                              size_t ws_size, hipStream_t stream) {
  const float* query = (const float*)d_in[0];
  const float* Wq = (const float*)d_in[1];
  const float* bq = (const float*)d_in[2];
  const float* Wk = (const float*)d_in[3];
  const float* bk = (const float*)d_in[4];
  const float* Wv = (const float*)d_in[5];
  const float* bv = (const float*)d_in[6];
  const float* Wo = (const float*)d_in[7];
  const float* bo = (const float*)d_in[8];
  float* out = (float*)d_out;

  float* fws = (float*)d_ws;
  float* sintab = fws;
  float* costab = fws + 65536;
  _Float16* Ah = (_Float16*)(fws + 131072);
  _Float16* Al = Ah + 4194304;
  _Float16* Wqh = Al + 4194304;
  _Float16* Wql = Wqh + 2097152;
  _Float16* Wkh = Wql + 2097152;
  _Float16* Wkl = Wkh + 1048576;
  _Float16* Wvh = Wkl + 1048576;
  _Float16* Wvl = Wvh + 1048576;
  _Float16* Woh = Wvl + 1048576;
  _Float16* Wol = Woh + 1048576;
  _Float16* qw = Wol + 1048576;   // (B,H,S,64)
  _Float16* kw = qw + 4194304;    // (B,H,S,64)
  _Float16* vtw = kw + 4194304;   // (B,H,64,S)
  _Float16* sg = vtw + 4194304;   // (B,S,D)
  _Float16* agh = Ah;             // reuse query-split space after QKV gemms
  _Float16* agl = Al;

  rope_table_kernel<<<256, 256, 0, stream>>>(sintab, costab);
  split_kernel<<<4096, 256, 0, stream>>>(query, Ah, Al, 1048576);
  split_kernel<<<2048, 256, 0, stream>>>(Wq, Wqh, Wql, 524288);
  split_kernel<<<1024, 256, 0, stream>>>(Wk, Wkh, Wkl, 262144);
  split_kernel<<<1024, 256, 0, stream>>>(Wv, Wvh, Wvl, 262144);
  split_kernel<<<1024, 256, 0, stream>>>(Wo, Woh, Wol, 262144);

  gemm_kernel<MODE_Q><<<dim3(16, 32), 256, 0, stream>>>(
      Ah, Al, Wqh, Wql, bq, qw, sg, nullptr, sintab, costab);
  gemm_kernel<MODE_K><<<dim3(8, 32), 256, 0, stream>>>(
      Ah, Al, Wkh, Wkl, bk, kw, nullptr, nullptr, sintab, costab);
  gemm_kernel<MODE_V><<<dim3(8, 32), 256, 0, stream>>>(
      Ah, Al, Wvh, Wvl, bv, vtw, nullptr, nullptr, sintab, costab);

  flash_kernel<<<dim3(32, 32), 256, 0, stream>>>(qw, kw, vtw, sg, agh, agl);

  gemm_kernel<MODE_O><<<dim3(8, 32), 256, 0, stream>>>(
      agh, agl, Woh, Wol, bo, nullptr, nullptr, out, sintab, costab);
}

// Round 3
// 295.371 us; speedup vs baseline: 4.0644x; 1.1568x over previous
//
#include <hip/hip_runtime.h>
#include <math.h>

#define SEQ 2048
#define DIMD 1024
#define NH 16
#define HDIM 64

#define MODE_Q 0
#define MODE_K 1
#define MODE_V 2
#define MODE_O 3

typedef _Float16 h8 __attribute__((ext_vector_type(8)));
typedef _Float16 h4 __attribute__((ext_vector_type(4)));
typedef float f32x4 __attribute__((ext_vector_type(4)));

// element-index swizzle for [64][64] f16 tiles (128B rows): XOR element bits
// 3-5 with (row&7).  Breaks the 16-lane same-column conflict.
__device__ __forceinline__ int SWE(int r, int c) {
  return ((r << 6) + c) ^ ((r & 7) << 3);
}

// ---------------------------------------------------------------------------
// RoPE table in double precision
// ---------------------------------------------------------------------------
__global__ void rope_table_kernel(float* __restrict__ sintab,
                                  float* __restrict__ costab) {
  int idx = blockIdx.x * 256 + threadIdx.x;  // 65536
  int t = idx >> 5;
  int i = idx & 31;
  double inv = pow(10000.0, -(double)(2 * i) / 64.0);
  double a = (double)t * inv;
  sintab[idx] = (float)sin(a);
  costab[idx] = (float)cos(a);
}

// ---------------------------------------------------------------------------
// f32 -> f16 hi/lo split
// ---------------------------------------------------------------------------
__global__ void split_kernel(const float* __restrict__ src,
                             _Float16* __restrict__ hi,
                             _Float16* __restrict__ lo, int n4) {
  int i = blockIdx.x * 256 + threadIdx.x;
  if (i >= n4) return;
  float4 v = ((const float4*)src)[i];
  h4 H, L;
  H[0] = (_Float16)v.x; L[0] = (_Float16)(v.x - (float)H[0]);
  H[1] = (_Float16)v.y; L[1] = (_Float16)(v.y - (float)H[1]);
  H[2] = (_Float16)v.z; L[2] = (_Float16)(v.z - (float)H[2]);
  H[3] = (_Float16)v.w; L[3] = (_Float16)(v.w - (float)H[3]);
  ((h4*)hi)[i] = H;
  ((h4*)lo)[i] = L;
}

// ---------------------------------------------------------------------------
// Split-f16 NT GEMM (3 MFMAs per frag pair): unchanged from round 2 except
// MODE_Q now folds SCALE=0.125 into the roped q values.
// ---------------------------------------------------------------------------
template <int MODE>
__global__ __launch_bounds__(256) void gemm_kernel(
    const _Float16* __restrict__ Ah, const _Float16* __restrict__ Al,
    const _Float16* __restrict__ Wh, const _Float16* __restrict__ Wl,
    const float* __restrict__ bias, _Float16* __restrict__ o16a,
    _Float16* __restrict__ o16b, float* __restrict__ o32,
    const float* __restrict__ sintab, const float* __restrict__ costab) {
  __shared__ _Float16 Ash[128][40];
  __shared__ _Float16 Asl[128][40];
  __shared__ _Float16 Bsh[128][40];
  __shared__ _Float16 Bsl[128][40];
  const int t = threadIdx.x;
  const int lane = t & 63;
  const int w = t >> 6;
  const int wm = w & 1, wn = w >> 1;
  const int fr = lane & 15;
  const int fk = (lane >> 4) * 8;
  const int m0 = blockIdx.y * 128, n0 = blockIdx.x * 128;

  f32x4 acc[4][4];
#pragma unroll
  for (int i = 0; i < 4; ++i)
#pragma unroll
    for (int j = 0; j < 4; ++j) acc[i][j] = (f32x4){0.f, 0.f, 0.f, 0.f};

  const int srow = t >> 1;
  const int sc = (t & 1) * 16;
  const _Float16* pAh = Ah + (size_t)(m0 + srow) * DIMD + sc;
  const _Float16* pAl = Al + (size_t)(m0 + srow) * DIMD + sc;
  const _Float16* pWh = Wh + (size_t)(n0 + srow) * DIMD + sc;
  const _Float16* pWl = Wl + (size_t)(n0 + srow) * DIMD + sc;

  for (int k0 = 0; k0 < DIMD; k0 += 32) {
    h8 rah0 = *(const h8*)(pAh + k0);
    h8 rah1 = *(const h8*)(pAh + k0 + 8);
    h8 ral0 = *(const h8*)(pAl + k0);
    h8 ral1 = *(const h8*)(pAl + k0 + 8);
    h8 rbh0 = *(const h8*)(pWh + k0);
    h8 rbh1 = *(const h8*)(pWh + k0 + 8);
    h8 rbl0 = *(const h8*)(pWl + k0);
    h8 rbl1 = *(const h8*)(pWl + k0 + 8);
    __syncthreads();
    *(h8*)&Ash[srow][sc] = rah0;
    *(h8*)&Ash[srow][sc + 8] = rah1;
    *(h8*)&Asl[srow][sc] = ral0;
    *(h8*)&Asl[srow][sc + 8] = ral1;
    *(h8*)&Bsh[srow][sc] = rbh0;
    *(h8*)&Bsh[srow][sc + 8] = rbh1;
    *(h8*)&Bsl[srow][sc] = rbl0;
    *(h8*)&Bsl[srow][sc + 8] = rbl1;
    __syncthreads();

    h8 ah[4], al[4], bh[4], bl[4];
#pragma unroll
    for (int mi = 0; mi < 4; ++mi) {
      ah[mi] = *(const h8*)&Ash[wm * 64 + mi * 16 + fr][fk];
      al[mi] = *(const h8*)&Asl[wm * 64 + mi * 16 + fr][fk];
    }
#pragma unroll
    for (int ni = 0; ni < 4; ++ni) {
      bh[ni] = *(const h8*)&Bsh[wn * 64 + ni * 16 + fr][fk];
      bl[ni] = *(const h8*)&Bsl[wn * 64 + ni * 16 + fr][fk];
    }
#pragma unroll
    for (int mi = 0; mi < 4; ++mi)
#pragma unroll
      for (int ni = 0; ni < 4; ++ni) {
        acc[mi][ni] = __builtin_amdgcn_mfma_f32_16x16x32_f16(
            ah[mi], bh[ni], acc[mi][ni], 0, 0, 0);
        acc[mi][ni] = __builtin_amdgcn_mfma_f32_16x16x32_f16(
            ah[mi], bl[ni], acc[mi][ni], 0, 0, 0);
        acc[mi][ni] = __builtin_amdgcn_mfma_f32_16x16x32_f16(
            al[mi], bh[ni], acc[mi][ni], 0, 0, 0);
      }
  }

  // Epilogue. C/D layout: col = lane&15, row = (lane>>4)*4 + reg.
#pragma unroll
  for (int mi = 0; mi < 4; ++mi)
#pragma unroll
    for (int ni = 0; ni < 4; ++ni) {
      const int col = n0 + wn * 64 + ni * 16 + fr;
      const float bsv = bias[col];
#pragma unroll
      for (int r = 0; r < 4; ++r) {
        const int row = m0 + wm * 64 + mi * 16 + (lane >> 4) * 4 + r;
        float v = acc[mi][ni][r] + bsv;
        const int b = row >> 11;
        const int s = row & (SEQ - 1);
        if (MODE == MODE_O) {
          o32[(size_t)row * DIMD + col] = v;
        } else if (MODE == MODE_V) {
          const int h = col >> 6, d = col & 63;
          o16a[((size_t)(b * NH + h) * HDIM + d) * SEQ + s] = (_Float16)v;
        } else if (MODE == MODE_K) {
          const int h = col >> 6, d = col & 63;
          float vp = __shfl_xor(v, 1);
          const int pi = s * 32 + (d >> 1);
          float sn = sintab[pi], cs = costab[pi];
          float rv = (d & 1) ? (vp * sn + v * cs) : (v * cs - vp * sn);
          o16a[((size_t)(b * NH + h) * SEQ + s) * HDIM + d] = (_Float16)rv;
        } else {  // MODE_Q
          const int h = n0 >> 7;
          const int d = col & 63;
          if (wn == 0) {  // q half: rope + SCALE
            float vp = __shfl_xor(v, 1);
            const int pi = s * 32 + (d >> 1);
            float sn = sintab[pi], cs = costab[pi];
            float rv = (d & 1) ? (vp * sn + v * cs) : (v * cs - vp * sn);
            rv *= 0.125f;  // attention scale folded in
            o16a[((size_t)(b * NH + h) * SEQ + s) * HDIM + d] = (_Float16)rv;
          } else {  // gate half: sigmoid -> (B,S,D)
            float g = 1.0f / (1.0f + __expf(-v));
            o16b[((size_t)(b * SEQ + s)) * DIMD + h * HDIM + d] = (_Float16)g;
          }
        }
      }
    }
}

// ---------------------------------------------------------------------------
// f16 MFMA flash attention, swapped-QK^T / in-register-P structure.
// Grid (S/128, B*H), 256 thr = 4 waves; wave owns 32 q-rows (2 col-frags).
// S^T = mfma(A=K, B=Q): lane's C-frag = 16 kv scores of ONE q-row (col fr).
// Softmax: in-lane over 16 + 2 shfl_xor (4 g-lanes share a q-row).
// PV with custom k<->kv order kv(8g+e,m)=16(2m+(e>>2))+4g+(e&3): each lane's
// own exp'd P values form the B-frag directly (no LDS, no cross-lane); V^T
// A-frags are two h4 LDS reads matching that order.  O^T accumulated.
// ---------------------------------------------------------------------------
__global__ __launch_bounds__(256) void flash_kernel(
    const _Float16* __restrict__ qh, const _Float16* __restrict__ kh,
    const _Float16* __restrict__ vt, const _Float16* __restrict__ sg,
    _Float16* __restrict__ agh, _Float16* __restrict__ agl) {
  __shared__ _Float16 K_lds[4096];
  __shared__ _Float16 Vt_lds[4096];
  const int t = threadIdx.x;
  const int lane = t & 63;
  const int w = t >> 6;
  const int fr = lane & 15;
  const int g = lane >> 4;
  const int bh = blockIdx.y;
  const int q0 = blockIdx.x * 128;
  const size_t kvbase = (size_t)bh * (SEQ * HDIM);

  // Q B-frags (hoisted): qb[jq][half]; B[k=d][j=q]: lane holds q=fr col,
  // d = 8g..8g+7 (+32*half), for q-row q0+32w+16jq+fr.
  h8 qb[2][2];
#pragma unroll
  for (int jq = 0; jq < 2; ++jq) {
    const _Float16* qp =
        qh + kvbase + (size_t)(q0 + 32 * w + 16 * jq + fr) * HDIM + 8 * g;
#pragma unroll
    for (int hh = 0; hh < 2; ++hh) qb[jq][hh] = *(const h8*)(qp + 32 * hh);
  }

  f32x4 oacc[2][4];
  float m_i[2], l_i[2];
#pragma unroll
  for (int jq = 0; jq < 2; ++jq) {
    m_i[jq] = -1e30f;
    l_i[jq] = 0.f;
#pragma unroll
    for (int df = 0; df < 4; ++df) oacc[jq][df] = (f32x4){0.f, 0.f, 0.f, 0.f};
  }

  const int srow = t >> 2;       // 0..63
  const int scb = (t & 3) * 16;  // 0,16,32,48
  const _Float16* kp = kh + kvbase;
  const _Float16* vp = vt + kvbase + (size_t)srow * SEQ;

  for (int j0 = 0; j0 < SEQ; j0 += 64) {
    h8 k0v = *(const h8*)(kp + (size_t)(j0 + srow) * HDIM + scb);
    h8 k1v = *(const h8*)(kp + (size_t)(j0 + srow) * HDIM + scb + 8);
    h8 v0v = *(const h8*)(vp + j0 + scb);
    h8 v1v = *(const h8*)(vp + j0 + scb + 8);
    __syncthreads();  // previous tile's frag reads complete
    *(h8*)&K_lds[SWE(srow, scb)] = k0v;
    *(h8*)&K_lds[SWE(srow, scb + 8)] = k1v;
    *(h8*)&Vt_lds[SWE(srow, scb)] = v0v;
    *(h8*)&Vt_lds[SWE(srow, scb + 8)] = v1v;
    __syncthreads();

    // S^T = K Q^T: sacc[jq][nf] covers kv rows 16nf..16nf+15, q col fr.
    f32x4 sacc[2][4];
#pragma unroll
    for (int jq = 0; jq < 2; ++jq)
#pragma unroll
      for (int nf = 0; nf < 4; ++nf) sacc[jq][nf] = (f32x4){0.f, 0.f, 0.f, 0.f};

    __builtin_amdgcn_s_setprio(1);
#pragma unroll
    for (int nf = 0; nf < 4; ++nf) {
      h8 ka0 = *(const h8*)&K_lds[SWE(16 * nf + fr, 8 * g)];
      h8 ka1 = *(const h8*)&K_lds[SWE(16 * nf + fr, 32 + 8 * g)];
      sacc[0][nf] = __builtin_amdgcn_mfma_f32_16x16x32_f16(ka0, qb[0][0],
                                                           sacc[0][nf], 0, 0, 0);
      sacc[0][nf] = __builtin_amdgcn_mfma_f32_16x16x32_f16(ka1, qb[0][1],
                                                           sacc[0][nf], 0, 0, 0);
      sacc[1][nf] = __builtin_amdgcn_mfma_f32_16x16x32_f16(ka0, qb[1][0],
                                                           sacc[1][nf], 0, 0, 0);
      sacc[1][nf] = __builtin_amdgcn_mfma_f32_16x16x32_f16(ka1, qb[1][1],
                                                           sacc[1][nf], 0, 0, 0);
    }
    __builtin_amdgcn_s_setprio(0);

    // In-register online softmax; lane's 16 values = kv {16nf+4g+r} of q=fr.
    h8 pb[2][2];
    float fct[2];
#pragma unroll
    for (int jq = 0; jq < 2; ++jq) {
      float mx = sacc[jq][0][0];
#pragma unroll
      for (int nf = 0; nf < 4; ++nf)
#pragma unroll
        for (int r = 0; r < 4; ++r) mx = fmaxf(mx, sacc[jq][nf][r]);
      mx = fmaxf(mx, __shfl_xor(mx, 16));
      mx = fmaxf(mx, __shfl_xor(mx, 32));
      float mn = fmaxf(m_i[jq], mx);
      float p[4][4];
      float rs = 0.f;
#pragma unroll
      for (int nf = 0; nf < 4; ++nf)
#pragma unroll
        for (int r = 0; r < 4; ++r) {
          p[nf][r] = __expf(sacc[jq][nf][r] - mn);
          rs += p[nf][r];
        }
      rs += __shfl_xor(rs, 16);
      rs += __shfl_xor(rs, 32);
      float f = __expf(m_i[jq] - mn);
      l_i[jq] = l_i[jq] * f + rs;
      m_i[jq] = mn;
      fct[jq] = f;
      // B-frag pack: pb[jq][m][e] = p[2m + (e>>2)][e&3]  (k = 8g+e)
#pragma unroll
      for (int m2 = 0; m2 < 2; ++m2) {
        h8 pk;
#pragma unroll
        for (int r = 0; r < 4; ++r) {
          pk[r] = (_Float16)p[2 * m2][r];
          pk[4 + r] = (_Float16)p[2 * m2 + 1][r];
        }
        pb[jq][m2] = pk;
      }
    }
#pragma unroll
    for (int jq = 0; jq < 2; ++jq) {
      f32x4 fv = (f32x4){fct[jq], fct[jq], fct[jq], fct[jq]};
#pragma unroll
      for (int df = 0; df < 4; ++df) oacc[jq][df] *= fv;
    }

    // O^T += V^T P^T : A-frag lane (fr,g) element e = V^T[16df+fr][kv(8g+e,m)]
    __builtin_amdgcn_s_setprio(1);
#pragma unroll
    for (int df = 0; df < 4; ++df) {
#pragma unroll
      for (int m2 = 0; m2 < 2; ++m2) {
        h4 vlo = *(const h4*)&Vt_lds[SWE(16 * df + fr, 32 * m2 + 4 * g)];
        h4 vhi = *(const h4*)&Vt_lds[SWE(16 * df + fr, 32 * m2 + 16 + 4 * g)];
        h8 va;
#pragma unroll
        for (int r = 0; r < 4; ++r) {
          va[r] = vlo[r];
          va[4 + r] = vhi[r];
        }
        oacc[0][df] = __builtin_amdgcn_mfma_f32_16x16x32_f16(va, pb[0][m2],
                                                             oacc[0][df], 0, 0, 0);
        oacc[1][df] = __builtin_amdgcn_mfma_f32_16x16x32_f16(va, pb[1][m2],
                                                             oacc[1][df], 0, 0, 0);
      }
    }
    __builtin_amdgcn_s_setprio(0);
  }

  // Epilogue: lane holds O^T[d=16df+4g+r][q=q0+32w+16jq+fr].
  const int b = bh >> 4, h = bh & 15;
#pragma unroll
  for (int jq = 0; jq < 2; ++jq) {
    const int qrow = q0 + 32 * w + 16 * jq + fr;
    const float inv = 1.0f / l_i[jq];
    const size_t obase = ((size_t)(b * SEQ + qrow)) * DIMD + h * HDIM;
#pragma unroll
    for (int df = 0; df < 4; ++df) {
      const int d0 = 16 * df + 4 * g;
      h4 gt = *(const h4*)&sg[obase + d0];
      h4 HI, LO;
#pragma unroll
      for (int r = 0; r < 4; ++r) {
        float val = oacc[jq][df][r] * inv * (float)gt[r];
        _Float16 hi = (_Float16)val;
        HI[r] = hi;
        LO[r] = (_Float16)(val - (float)hi);
      }
      *(h4*)&agh[obase + d0] = HI;
      *(h4*)&agl[obase + d0] = LO;
    }
  }
}

// ---------------------------------------------------------------------------
extern "C" void kernel_launch(void* const* d_in, const int* in_sizes, int n_in,
                              void* d_out, int out_size, void* d_ws,
                              size_t ws_size, hipStream_t stream) {
  const float* query = (const float*)d_in[0];
  const float* Wq = (const float*)d_in[1];
  const float* bq = (const float*)d_in[2];
  const float* Wk = (const float*)d_in[3];
  const float* bk = (const float*)d_in[4];
  const float* Wv = (const float*)d_in[5];
  const float* bv = (const float*)d_in[6];
  const float* Wo = (const float*)d_in[7];
  const float* bo = (const float*)d_in[8];
  float* out = (float*)d_out;

  float* fws = (float*)d_ws;
  float* sintab = fws;
  float* costab = fws + 65536;
  _Float16* Ah = (_Float16*)(fws + 131072);
  _Float16* Al = Ah + 4194304;
  _Float16* Wqh = Al + 4194304;
  _Float16* Wql = Wqh + 2097152;
  _Float16* Wkh = Wql + 2097152;
  _Float16* Wkl = Wkh + 1048576;
  _Float16* Wvh = Wkl + 1048576;
  _Float16* Wvl = Wvh + 1048576;
  _Float16* Woh = Wvl + 1048576;
  _Float16* Wol = Woh + 1048576;
  _Float16* qw = Wol + 1048576;   // (B,H,S,64) q, roped, pre-scaled
  _Float16* kw = qw + 4194304;    // (B,H,S,64) k, roped
  _Float16* vtw = kw + 4194304;   // (B,H,64,S) v transposed
  _Float16* sg = vtw + 4194304;   // (B,S,D) sigmoid(gate)
  _Float16* agh = Ah;             // reuse query-split space after QKV gemms
  _Float16* agl = Al;

  rope_table_kernel<<<256, 256, 0, stream>>>(sintab, costab);
  split_kernel<<<4096, 256, 0, stream>>>(query, Ah, Al, 1048576);
  split_kernel<<<2048, 256, 0, stream>>>(Wq, Wqh, Wql, 524288);
  split_kernel<<<1024, 256, 0, stream>>>(Wk, Wkh, Wkl, 262144);
  split_kernel<<<1024, 256, 0, stream>>>(Wv, Wvh, Wvl, 262144);
  split_kernel<<<1024, 256, 0, stream>>>(Wo, Woh, Wol, 262144);

  gemm_kernel<MODE_Q><<<dim3(16, 32), 256, 0, stream>>>(
      Ah, Al, Wqh, Wql, bq, qw, sg, nullptr, sintab, costab);
  gemm_kernel<MODE_K><<<dim3(8, 32), 256, 0, stream>>>(
      Ah, Al, Wkh, Wkl, bk, kw, nullptr, nullptr, sintab, costab);
  gemm_kernel<MODE_V><<<dim3(8, 32), 256, 0, stream>>>(
      Ah, Al, Wvh, Wvl, bv, vtw, nullptr, nullptr, sintab, costab);

  flash_kernel<<<dim3(16, 32), 256, 0, stream>>>(qw, kw, vtw, sg, agh, agl);

  gemm_kernel<MODE_O><<<dim3(8, 32), 256, 0, stream>>>(
      agh, agl, Woh, Wol, bo, nullptr, nullptr, out, sintab, costab);
}

// Round 5
// 234.095 us; speedup vs baseline: 5.1282x; 1.2618x over previous
//
#include <hip/hip_runtime.h>
#include <math.h>

#define SEQ 2048
#define DIMD 1024
#define NH 16
#define HDIM 64

#define MODE_Q 0
#define MODE_K 1
#define MODE_V 2
#define MODE_O 3

typedef _Float16 h8 __attribute__((ext_vector_type(8)));
typedef _Float16 h4 __attribute__((ext_vector_type(4)));
typedef __fp16 fp16x2 __attribute__((ext_vector_type(2)));
typedef float f32x4 __attribute__((ext_vector_type(4)));

// element-index swizzle for [64][64] f16 tiles (128B rows): XOR element bits
// 3-5 with (row&7).  Breaks the 16-lane same-column conflict.
__device__ __forceinline__ int SWE(int r, int c) {
  return ((r << 6) + c) ^ ((r & 7) << 3);
}

// ---------------------------------------------------------------------------
// RoPE table in double precision
// ---------------------------------------------------------------------------
__global__ void rope_table_kernel(float* __restrict__ sintab,
                                  float* __restrict__ costab) {
  int idx = blockIdx.x * 256 + threadIdx.x;  // 65536
  int t = idx >> 5;
  int i = idx & 31;
  double inv = pow(10000.0, -(double)(2 * i) / 64.0);
  double a = (double)t * inv;
  sintab[idx] = (float)sin(a);
  costab[idx] = (float)cos(a);
}

// ---------------------------------------------------------------------------
// f32 -> f16 plain convert (QKV path needs no split; see round-3 analysis)
// ---------------------------------------------------------------------------
__global__ void convert_kernel(const float* __restrict__ src,
                               _Float16* __restrict__ dst, int n4) {
  int i = blockIdx.x * 256 + threadIdx.x;
  if (i >= n4) return;
  float4 v = ((const float4*)src)[i];
  h4 H;
  H[0] = (_Float16)v.x;
  H[1] = (_Float16)v.y;
  H[2] = (_Float16)v.z;
  H[3] = (_Float16)v.w;
  ((h4*)dst)[i] = H;
}

// ---------------------------------------------------------------------------
// f32 -> f16 hi/lo split (only Wo now)
// ---------------------------------------------------------------------------
__global__ void split_kernel(const float* __restrict__ src,
                             _Float16* __restrict__ hi,
                             _Float16* __restrict__ lo, int n4) {
  int i = blockIdx.x * 256 + threadIdx.x;
  if (i >= n4) return;
  float4 v = ((const float4*)src)[i];
  h4 H, L;
  H[0] = (_Float16)v.x; L[0] = (_Float16)(v.x - (float)H[0]);
  H[1] = (_Float16)v.y; L[1] = (_Float16)(v.y - (float)H[1]);
  H[2] = (_Float16)v.z; L[2] = (_Float16)(v.z - (float)H[2]);
  H[3] = (_Float16)v.w; L[3] = (_Float16)(v.w - (float)H[3]);
  ((h4*)hi)[i] = H;
  ((h4*)lo)[i] = L;
}

// ---------------------------------------------------------------------------
// f16 NT GEMM, optionally hi/lo split (3 MFMAs per frag pair when SPLIT).
// Tile 128x128, BK=32, 4 waves of 64x64 (4x4 frags of 16x16x32).
// MODE_Q folds SCALE=0.125 into roped q.
// ---------------------------------------------------------------------------
template <int MODE, bool SPLIT>
__global__ __launch_bounds__(256) void gemm_kernel(
    const _Float16* __restrict__ Ah, const _Float16* __restrict__ Al,
    const _Float16* __restrict__ Wh, const _Float16* __restrict__ Wl,
    const float* __restrict__ bias, _Float16* __restrict__ o16a,
    _Float16* __restrict__ o16b, float* __restrict__ o32,
    const float* __restrict__ sintab, const float* __restrict__ costab) {
  __shared__ _Float16 Ash[128][40];
  __shared__ _Float16 Bsh[128][40];
  __shared__ _Float16 Asl[SPLIT ? 128 : 1][40];
  __shared__ _Float16 Bsl[SPLIT ? 128 : 1][40];
  const int t = threadIdx.x;
  const int lane = t & 63;
  const int w = t >> 6;
  const int wm = w & 1, wn = w >> 1;
  const int fr = lane & 15;
  const int fk = (lane >> 4) * 8;
  const int m0 = blockIdx.y * 128, n0 = blockIdx.x * 128;

  f32x4 acc[4][4];
#pragma unroll
  for (int i = 0; i < 4; ++i)
#pragma unroll
    for (int j = 0; j < 4; ++j) acc[i][j] = (f32x4){0.f, 0.f, 0.f, 0.f};

  const int srow = t >> 1;
  const int sc = (t & 1) * 16;
  const _Float16* pAh = Ah + (size_t)(m0 + srow) * DIMD + sc;
  const _Float16* pWh = Wh + (size_t)(n0 + srow) * DIMD + sc;
  const _Float16* pAl = SPLIT ? Al + (size_t)(m0 + srow) * DIMD + sc : nullptr;
  const _Float16* pWl = SPLIT ? Wl + (size_t)(n0 + srow) * DIMD + sc : nullptr;

  for (int k0 = 0; k0 < DIMD; k0 += 32) {
    h8 rah0 = *(const h8*)(pAh + k0);
    h8 rah1 = *(const h8*)(pAh + k0 + 8);
    h8 rbh0 = *(const h8*)(pWh + k0);
    h8 rbh1 = *(const h8*)(pWh + k0 + 8);
    h8 ral0, ral1, rbl0, rbl1;
    if constexpr (SPLIT) {
      ral0 = *(const h8*)(pAl + k0);
      ral1 = *(const h8*)(pAl + k0 + 8);
      rbl0 = *(const h8*)(pWl + k0);
      rbl1 = *(const h8*)(pWl + k0 + 8);
    }
    __syncthreads();
    *(h8*)&Ash[srow][sc] = rah0;
    *(h8*)&Ash[srow][sc + 8] = rah1;
    *(h8*)&Bsh[srow][sc] = rbh0;
    *(h8*)&Bsh[srow][sc + 8] = rbh1;
    if constexpr (SPLIT) {
      *(h8*)&Asl[srow][sc] = ral0;
      *(h8*)&Asl[srow][sc + 8] = ral1;
      *(h8*)&Bsl[srow][sc] = rbl0;
      *(h8*)&Bsl[srow][sc + 8] = rbl1;
    }
    __syncthreads();

    h8 ah[4], bh[4], al[4], bl[4];
#pragma unroll
    for (int mi = 0; mi < 4; ++mi)
      ah[mi] = *(const h8*)&Ash[wm * 64 + mi * 16 + fr][fk];
#pragma unroll
    for (int ni = 0; ni < 4; ++ni)
      bh[ni] = *(const h8*)&Bsh[wn * 64 + ni * 16 + fr][fk];
    if constexpr (SPLIT) {
#pragma unroll
      for (int mi = 0; mi < 4; ++mi)
        al[mi] = *(const h8*)&Asl[wm * 64 + mi * 16 + fr][fk];
#pragma unroll
      for (int ni = 0; ni < 4; ++ni)
        bl[ni] = *(const h8*)&Bsl[wn * 64 + ni * 16 + fr][fk];
    }
#pragma unroll
    for (int mi = 0; mi < 4; ++mi)
#pragma unroll
      for (int ni = 0; ni < 4; ++ni) {
        acc[mi][ni] = __builtin_amdgcn_mfma_f32_16x16x32_f16(
            ah[mi], bh[ni], acc[mi][ni], 0, 0, 0);
        if constexpr (SPLIT) {
          acc[mi][ni] = __builtin_amdgcn_mfma_f32_16x16x32_f16(
              ah[mi], bl[ni], acc[mi][ni], 0, 0, 0);
          acc[mi][ni] = __builtin_amdgcn_mfma_f32_16x16x32_f16(
              al[mi], bh[ni], acc[mi][ni], 0, 0, 0);
        }
      }
  }

  // Epilogue. C/D layout: col = lane&15, row = (lane>>4)*4 + reg.
#pragma unroll
  for (int mi = 0; mi < 4; ++mi)
#pragma unroll
    for (int ni = 0; ni < 4; ++ni) {
      const int col = n0 + wn * 64 + ni * 16 + fr;
      const float bsv = bias[col];
#pragma unroll
      for (int r = 0; r < 4; ++r) {
        const int row = m0 + wm * 64 + mi * 16 + (lane >> 4) * 4 + r;
        float v = acc[mi][ni][r] + bsv;
        const int b = row >> 11;
        const int s = row & (SEQ - 1);
        if (MODE == MODE_O) {
          o32[(size_t)row * DIMD + col] = v;
        } else if (MODE == MODE_V) {
          const int h = col >> 6, d = col & 63;
          o16a[((size_t)(b * NH + h) * HDIM + d) * SEQ + s] = (_Float16)v;
        } else if (MODE == MODE_K) {
          const int h = col >> 6, d = col & 63;
          float vp = __shfl_xor(v, 1);
          const int pi = s * 32 + (d >> 1);
          float sn = sintab[pi], cs = costab[pi];
          float rv = (d & 1) ? (vp * sn + v * cs) : (v * cs - vp * sn);
          o16a[((size_t)(b * NH + h) * SEQ + s) * HDIM + d] = (_Float16)rv;
        } else {  // MODE_Q
          const int h = n0 >> 7;
          const int d = col & 63;
          if (wn == 0) {  // q half: rope + SCALE
            float vp = __shfl_xor(v, 1);
            const int pi = s * 32 + (d >> 1);
            float sn = sintab[pi], cs = costab[pi];
            float rv = (d & 1) ? (vp * sn + v * cs) : (v * cs - vp * sn);
            rv *= 0.125f;  // attention scale folded in
            o16a[((size_t)(b * NH + h) * SEQ + s) * HDIM + d] = (_Float16)rv;
          } else {  // gate half: sigmoid -> (B,S,D)
            float g = 1.0f / (1.0f + __expf(-v));
            o16b[((size_t)(b * SEQ + s)) * DIMD + h * HDIM + d] = (_Float16)g;
          }
        }
      }
    }
}

// ---------------------------------------------------------------------------
// f16 MFMA flash attention, swapped-QK^T / in-register-P structure.
// Adds: defer-max (THR=8, wave-uniform), v_cvt_pkrtz P packing,
// max3-friendly reduction.
// ---------------------------------------------------------------------------
__global__ __launch_bounds__(256) void flash_kernel(
    const _Float16* __restrict__ qh, const _Float16* __restrict__ kh,
    const _Float16* __restrict__ vt, const _Float16* __restrict__ sg,
    _Float16* __restrict__ agh, _Float16* __restrict__ agl) {
  __shared__ _Float16 K_lds[4096];
  __shared__ _Float16 Vt_lds[4096];
  const int t = threadIdx.x;
  const int lane = t & 63;
  const int w = t >> 6;
  const int fr = lane & 15;
  const int g = lane >> 4;
  const int bh = blockIdx.y;
  const int q0 = blockIdx.x * 128;
  const size_t kvbase = (size_t)bh * (SEQ * HDIM);

  h8 qb[2][2];
#pragma unroll
  for (int jq = 0; jq < 2; ++jq) {
    const _Float16* qp =
        qh + kvbase + (size_t)(q0 + 32 * w + 16 * jq + fr) * HDIM + 8 * g;
#pragma unroll
    for (int hh = 0; hh < 2; ++hh) qb[jq][hh] = *(const h8*)(qp + 32 * hh);
  }

  f32x4 oacc[2][4];
  float m_i[2], l_i[2];
#pragma unroll
  for (int jq = 0; jq < 2; ++jq) {
    m_i[jq] = -1e30f;
    l_i[jq] = 0.f;
#pragma unroll
    for (int df = 0; df < 4; ++df) oacc[jq][df] = (f32x4){0.f, 0.f, 0.f, 0.f};
  }

  const int srow = t >> 2;       // 0..63
  const int scb = (t & 3) * 16;  // 0,16,32,48
  const _Float16* kp = kh + kvbase;
  const _Float16* vp = vt + kvbase + (size_t)srow * SEQ;

  for (int j0 = 0; j0 < SEQ; j0 += 64) {
    h8 k0v = *(const h8*)(kp + (size_t)(j0 + srow) * HDIM + scb);
    h8 k1v = *(const h8*)(kp + (size_t)(j0 + srow) * HDIM + scb + 8);
    h8 v0v = *(const h8*)(vp + j0 + scb);
    h8 v1v = *(const h8*)(vp + j0 + scb + 8);
    __syncthreads();  // previous tile's frag reads complete
    *(h8*)&K_lds[SWE(srow, scb)] = k0v;
    *(h8*)&K_lds[SWE(srow, scb + 8)] = k1v;
    *(h8*)&Vt_lds[SWE(srow, scb)] = v0v;
    *(h8*)&Vt_lds[SWE(srow, scb + 8)] = v1v;
    __syncthreads();

    // S^T = K Q^T
    f32x4 sacc[2][4];
#pragma unroll
    for (int jq = 0; jq < 2; ++jq)
#pragma unroll
      for (int nf = 0; nf < 4; ++nf) sacc[jq][nf] = (f32x4){0.f, 0.f, 0.f, 0.f};

    __builtin_amdgcn_s_setprio(1);
#pragma unroll
    for (int nf = 0; nf < 4; ++nf) {
      h8 ka0 = *(const h8*)&K_lds[SWE(16 * nf + fr, 8 * g)];
      h8 ka1 = *(const h8*)&K_lds[SWE(16 * nf + fr, 32 + 8 * g)];
      sacc[0][nf] = __builtin_amdgcn_mfma_f32_16x16x32_f16(ka0, qb[0][0],
                                                           sacc[0][nf], 0, 0, 0);
      sacc[0][nf] = __builtin_amdgcn_mfma_f32_16x16x32_f16(ka1, qb[0][1],
                                                           sacc[0][nf], 0, 0, 0);
      sacc[1][nf] = __builtin_amdgcn_mfma_f32_16x16x32_f16(ka0, qb[1][0],
                                                           sacc[1][nf], 0, 0, 0);
      sacc[1][nf] = __builtin_amdgcn_mfma_f32_16x16x32_f16(ka1, qb[1][1],
                                                           sacc[1][nf], 0, 0, 0);
    }
    __builtin_amdgcn_s_setprio(0);

    // In-register online softmax with defer-max (THR=8).
    h8 pb[2][2];
#pragma unroll
    for (int jq = 0; jq < 2; ++jq) {
      // max over 16 in-lane values (max3-friendly triples) + 2 shfl
      float m0 = fmaxf(fmaxf(sacc[jq][0][0], sacc[jq][0][1]), sacc[jq][0][2]);
      float m1 = fmaxf(fmaxf(sacc[jq][0][3], sacc[jq][1][0]), sacc[jq][1][1]);
      float m2 = fmaxf(fmaxf(sacc[jq][1][2], sacc[jq][1][3]), sacc[jq][2][0]);
      float m3 = fmaxf(fmaxf(sacc[jq][2][1], sacc[jq][2][2]), sacc[jq][2][3]);
      float m4 = fmaxf(fmaxf(sacc[jq][3][0], sacc[jq][3][1]), sacc[jq][3][2]);
      float mx = fmaxf(fmaxf(fmaxf(fmaxf(m0, m1), m2), fmaxf(m3, m4)),
                       sacc[jq][3][3]);
      mx = fmaxf(mx, __shfl_xor(mx, 16));
      mx = fmaxf(mx, __shfl_xor(mx, 32));
      const int allskip = __all(mx <= m_i[jq] + 8.0f);
      const float mn = allskip ? m_i[jq] : fmaxf(m_i[jq], mx);
      float p[4][4];
      float rs = 0.f;
#pragma unroll
      for (int nf = 0; nf < 4; ++nf)
#pragma unroll
        for (int r = 0; r < 4; ++r) {
          p[nf][r] = __expf(sacc[jq][nf][r] - mn);
          rs += p[nf][r];
        }
      rs += __shfl_xor(rs, 16);
      rs += __shfl_xor(rs, 32);
      if (allskip) {
        l_i[jq] += rs;
      } else {
        float f = __expf(m_i[jq] - mn);
        l_i[jq] = l_i[jq] * f + rs;
        m_i[jq] = mn;
        f32x4 fv = (f32x4){f, f, f, f};
#pragma unroll
        for (int df = 0; df < 4; ++df) oacc[jq][df] *= fv;
      }
      // B-frag pack via packed f32->f16: pb[m2] elems = p[2m2][0..3],p[2m2+1][0..3]
#pragma unroll
      for (int m2 = 0; m2 < 2; ++m2) {
        union {
          h8 v;
          fp16x2 h[4];
        } u;
        u.h[0] = __builtin_amdgcn_cvt_pkrtz(p[2 * m2][0], p[2 * m2][1]);
        u.h[1] = __builtin_amdgcn_cvt_pkrtz(p[2 * m2][2], p[2 * m2][3]);
        u.h[2] = __builtin_amdgcn_cvt_pkrtz(p[2 * m2 + 1][0], p[2 * m2 + 1][1]);
        u.h[3] = __builtin_amdgcn_cvt_pkrtz(p[2 * m2 + 1][2], p[2 * m2 + 1][3]);
        pb[jq][m2] = u.v;
      }
    }

    // O^T += V^T P^T
    __builtin_amdgcn_s_setprio(1);
#pragma unroll
    for (int df = 0; df < 4; ++df) {
#pragma unroll
      for (int m2 = 0; m2 < 2; ++m2) {
        h4 vlo = *(const h4*)&Vt_lds[SWE(16 * df + fr, 32 * m2 + 4 * g)];
        h4 vhi = *(const h4*)&Vt_lds[SWE(16 * df + fr, 32 * m2 + 16 + 4 * g)];
        h8 va;
#pragma unroll
        for (int r = 0; r < 4; ++r) {
          va[r] = vlo[r];
          va[4 + r] = vhi[r];
        }
        oacc[0][df] = __builtin_amdgcn_mfma_f32_16x16x32_f16(va, pb[0][m2],
                                                             oacc[0][df], 0, 0, 0);
        oacc[1][df] = __builtin_amdgcn_mfma_f32_16x16x32_f16(va, pb[1][m2],
                                                             oacc[1][df], 0, 0, 0);
      }
    }
    __builtin_amdgcn_s_setprio(0);
  }

  // Epilogue: lane holds O^T[d=16df+4g+r][q=q0+32w+16jq+fr].
  const int b = bh >> 4, h = bh & 15;
#pragma unroll
  for (int jq = 0; jq < 2; ++jq) {
    const int qrow = q0 + 32 * w + 16 * jq + fr;
    const float inv = 1.0f / l_i[jq];
    const size_t obase = ((size_t)(b * SEQ + qrow)) * DIMD + h * HDIM;
#pragma unroll
    for (int df = 0; df < 4; ++df) {
      const int d0 = 16 * df + 4 * g;
      h4 gt = *(const h4*)&sg[obase + d0];
      h4 HI, LO;
#pragma unroll
      for (int r = 0; r < 4; ++r) {
        float val = oacc[jq][df][r] * inv * (float)gt[r];
        _Float16 hi = (_Float16)val;
        HI[r] = hi;
        LO[r] = (_Float16)(val - (float)hi);
      }
      *(h4*)&agh[obase + d0] = HI;
      *(h4*)&agl[obase + d0] = LO;
    }
  }
}

// ---------------------------------------------------------------------------
extern "C" void kernel_launch(void* const* d_in, const int* in_sizes, int n_in,
                              void* d_out, int out_size, void* d_ws,
                              size_t ws_size, hipStream_t stream) {
  const float* query = (const float*)d_in[0];
  const float* Wq = (const float*)d_in[1];
  const float* bq = (const float*)d_in[2];
  const float* Wk = (const float*)d_in[3];
  const float* bk = (const float*)d_in[4];
  const float* Wv = (const float*)d_in[5];
  const float* bv = (const float*)d_in[6];
  const float* Wo = (const float*)d_in[7];
  const float* bo = (const float*)d_in[8];
  float* out = (float*)d_out;

  float* fws = (float*)d_ws;
  float* sintab = fws;
  float* costab = fws + 65536;
  _Float16* Ah = (_Float16*)(fws + 131072);  // query f16 / later agh
  _Float16* Al = Ah + 4194304;               // (unused) / later agl
  _Float16* Wqh = Al + 4194304;
  _Float16* Wql = Wqh + 2097152;  // unused
  _Float16* Wkh = Wql + 2097152;
  _Float16* Wkl = Wkh + 1048576;  // unused
  _Float16* Wvh = Wkl + 1048576;
  _Float16* Wvl = Wvh + 1048576;  // unused
  _Float16* Woh = Wvl + 1048576;
  _Float16* Wol = Woh + 1048576;
  _Float16* qw = Wol + 1048576;   // (B,H,S,64) q, roped, pre-scaled
  _Float16* kw = qw + 4194304;    // (B,H,S,64) k, roped
  _Float16* vtw = kw + 4194304;   // (B,H,64,S) v transposed
  _Float16* sg = vtw + 4194304;   // (B,S,D) sigmoid(gate)
  _Float16* agh = Ah;             // reuse after QKV gemms
  _Float16* agl = Al;

  rope_table_kernel<<<256, 256, 0, stream>>>(sintab, costab);
  convert_kernel<<<4096, 256, 0, stream>>>(query, Ah, 1048576);
  convert_kernel<<<2048, 256, 0, stream>>>(Wq, Wqh, 524288);
  convert_kernel<<<1024, 256, 0, stream>>>(Wk, Wkh, 262144);
  convert_kernel<<<1024, 256, 0, stream>>>(Wv, Wvh, 262144);
  split_kernel<<<1024, 256, 0, stream>>>(Wo, Woh, Wol, 262144);

  gemm_kernel<MODE_Q, false><<<dim3(16, 32), 256, 0, stream>>>(
      Ah, nullptr, Wqh, nullptr, bq, qw, sg, nullptr, sintab, costab);
  gemm_kernel<MODE_K, false><<<dim3(8, 32), 256, 0, stream>>>(
      Ah, nullptr, Wkh, nullptr, bk, kw, nullptr, nullptr, sintab, costab);
  gemm_kernel<MODE_V, false><<<dim3(8, 32), 256, 0, stream>>>(
      Ah, nullptr, Wvh, nullptr, bv, vtw, nullptr, nullptr, sintab, costab);

  flash_kernel<<<dim3(16, 32), 256, 0, stream>>>(qw, kw, vtw, sg, agh, agl);

  gemm_kernel<MODE_O, true><<<dim3(8, 32), 256, 0, stream>>>(
      agh, agl, Woh, Wol, bo, nullptr, nullptr, out, sintab, costab);
}

// Round 6
// 205.515 us; speedup vs baseline: 5.8414x; 1.1391x over previous
//
#include <hip/hip_runtime.h>
#include <math.h>

#define SEQ 2048
#define DIMD 1024
#define NH 16
#define HDIM 64

typedef _Float16 h8 __attribute__((ext_vector_type(8)));
typedef _Float16 h4 __attribute__((ext_vector_type(4)));
typedef __fp16 fp16x2 __attribute__((ext_vector_type(2)));
typedef float f32x4 __attribute__((ext_vector_type(4)));

// element-index swizzle for [64][64] f16 tiles (128B rows): XOR element bits
// 3-5 with (row&7).  Breaks the 16-lane same-column conflict.
__device__ __forceinline__ int SWE(int r, int c) {
  return ((r << 6) + c) ^ ((r & 7) << 3);
}

// ---------------------------------------------------------------------------
// RoPE table in double precision
// ---------------------------------------------------------------------------
__global__ void rope_table_kernel(float* __restrict__ sintab,
                                  float* __restrict__ costab) {
  int idx = blockIdx.x * 256 + threadIdx.x;  // 65536
  int t = idx >> 5;
  int i = idx & 31;
  double inv = pow(10000.0, -(double)(2 * i) / 64.0);
  double a = (double)t * inv;
  sintab[idx] = (float)sin(a);
  costab[idx] = (float)cos(a);
}

// ---------------------------------------------------------------------------
// f32 -> f16 plain convert
// ---------------------------------------------------------------------------
__global__ void convert_kernel(const float* __restrict__ src,
                               _Float16* __restrict__ dst, int n4) {
  int i = blockIdx.x * 256 + threadIdx.x;
  if (i >= n4) return;
  float4 v = ((const float4*)src)[i];
  h4 H;
  H[0] = (_Float16)v.x;
  H[1] = (_Float16)v.y;
  H[2] = (_Float16)v.z;
  H[3] = (_Float16)v.w;
  ((h4*)dst)[i] = H;
}

// ---------------------------------------------------------------------------
// f32 -> f16 hi/lo split (Wo only)
// ---------------------------------------------------------------------------
__global__ void split_kernel(const float* __restrict__ src,
                             _Float16* __restrict__ hi,
                             _Float16* __restrict__ lo, int n4) {
  int i = blockIdx.x * 256 + threadIdx.x;
  if (i >= n4) return;
  float4 v = ((const float4*)src)[i];
  h4 H, L;
  H[0] = (_Float16)v.x; L[0] = (_Float16)(v.x - (float)H[0]);
  H[1] = (_Float16)v.y; L[1] = (_Float16)(v.y - (float)H[1]);
  H[2] = (_Float16)v.z; L[2] = (_Float16)(v.z - (float)H[2]);
  H[3] = (_Float16)v.w; L[3] = (_Float16)(v.w - (float)H[3]);
  ((h4*)hi)[i] = H;
  ((h4*)lo)[i] = L;
}

// ---------------------------------------------------------------------------
// Fused QKV projection GEMM over concat N=4096 (q|gate 2048, k 1024, v 1024).
// Tile 128x128, BK=32, 4 waves of 64x64 (4x4 frags of 16x16x32), grid 32x32
// = 1024 blocks (4/CU).  Region picked per n0 (uniform).  Epilogues: rope+
// scale q, sigmoid gate, rope k, transpose v.
// ---------------------------------------------------------------------------
__global__ __launch_bounds__(256) void qkv_kernel(
    const _Float16* __restrict__ Ah, const _Float16* __restrict__ Wqh,
    const _Float16* __restrict__ Wkh, const _Float16* __restrict__ Wvh,
    const float* __restrict__ bq, const float* __restrict__ bk,
    const float* __restrict__ bv, _Float16* __restrict__ qw,
    _Float16* __restrict__ sg, _Float16* __restrict__ kw,
    _Float16* __restrict__ vtw, const float* __restrict__ sintab,
    const float* __restrict__ costab) {
  __shared__ _Float16 Ash[128][40];
  __shared__ _Float16 Bsh[128][40];
  const int t = threadIdx.x;
  const int lane = t & 63;
  const int w = t >> 6;
  const int wm = w & 1, wn = w >> 1;
  const int fr = lane & 15;
  const int fk = (lane >> 4) * 8;
  const int m0 = blockIdx.y * 128;
  const int n0 = blockIdx.x * 128;
  const int region = (n0 < 2048) ? 0 : (n0 < 3072 ? 1 : 2);
  const _Float16* Wb = region == 0   ? Wqh + (size_t)n0 * DIMD
                       : region == 1 ? Wkh + (size_t)(n0 - 2048) * DIMD
                                     : Wvh + (size_t)(n0 - 3072) * DIMD;
  const float* bias = region == 0   ? bq + n0
                      : region == 1 ? bk + (n0 - 2048)
                                    : bv + (n0 - 3072);

  f32x4 acc[4][4];
#pragma unroll
  for (int i = 0; i < 4; ++i)
#pragma unroll
    for (int j = 0; j < 4; ++j) acc[i][j] = (f32x4){0.f, 0.f, 0.f, 0.f};

  const int srow = t >> 1;
  const int sc = (t & 1) * 16;
  const _Float16* pA = Ah + (size_t)(m0 + srow) * DIMD + sc;
  const _Float16* pW = Wb + (size_t)srow * DIMD + sc;

  for (int k0 = 0; k0 < DIMD; k0 += 32) {
    h8 ra0 = *(const h8*)(pA + k0);
    h8 ra1 = *(const h8*)(pA + k0 + 8);
    h8 rb0 = *(const h8*)(pW + k0);
    h8 rb1 = *(const h8*)(pW + k0 + 8);
    __syncthreads();
    *(h8*)&Ash[srow][sc] = ra0;
    *(h8*)&Ash[srow][sc + 8] = ra1;
    *(h8*)&Bsh[srow][sc] = rb0;
    *(h8*)&Bsh[srow][sc + 8] = rb1;
    __syncthreads();

    h8 ah[4], bh[4];
#pragma unroll
    for (int mi = 0; mi < 4; ++mi)
      ah[mi] = *(const h8*)&Ash[wm * 64 + mi * 16 + fr][fk];
#pragma unroll
    for (int ni = 0; ni < 4; ++ni)
      bh[ni] = *(const h8*)&Bsh[wn * 64 + ni * 16 + fr][fk];
#pragma unroll
    for (int mi = 0; mi < 4; ++mi)
#pragma unroll
      for (int ni = 0; ni < 4; ++ni)
        acc[mi][ni] = __builtin_amdgcn_mfma_f32_16x16x32_f16(
            ah[mi], bh[ni], acc[mi][ni], 0, 0, 0);
  }

  // Epilogue. C/D layout: col = lane&15, row = (lane>>4)*4 + reg.
#pragma unroll
  for (int mi = 0; mi < 4; ++mi)
#pragma unroll
    for (int ni = 0; ni < 4; ++ni) {
      const int cl = wn * 64 + ni * 16 + fr;  // col within tile
      const float bsv = bias[cl];
#pragma unroll
      for (int r = 0; r < 4; ++r) {
        const int row = m0 + wm * 64 + mi * 16 + (lane >> 4) * 4 + r;
        float v = acc[mi][ni][r] + bsv;
        const int b = row >> 11;
        const int s = row & (SEQ - 1);
        if (region == 0) {
          const int h = n0 >> 7;
          const int d = cl & 63;
          if (wn == 0) {  // q: rope + SCALE
            float vp = __shfl_xor(v, 1);
            const int pi = s * 32 + (d >> 1);
            float sn = sintab[pi], cs = costab[pi];
            float rv = (d & 1) ? (vp * sn + v * cs) : (v * cs - vp * sn);
            rv *= 0.125f;
            qw[((size_t)(b * NH + h) * SEQ + s) * HDIM + d] = (_Float16)rv;
          } else {  // gate: sigmoid -> (B,S,D)
            float g = 1.0f / (1.0f + __expf(-v));
            sg[((size_t)(b * SEQ + s)) * DIMD + h * HDIM + d] = (_Float16)g;
          }
        } else if (region == 1) {
          const int kc = (n0 - 2048) + cl;
          const int h = kc >> 6, d = kc & 63;
          float vp = __shfl_xor(v, 1);
          const int pi = s * 32 + (d >> 1);
          float sn = sintab[pi], cs = costab[pi];
          float rv = (d & 1) ? (vp * sn + v * cs) : (v * cs - vp * sn);
          kw[((size_t)(b * NH + h) * SEQ + s) * HDIM + d] = (_Float16)rv;
        } else {
          const int vc = (n0 - 3072) + cl;
          const int h = vc >> 6, d = vc & 63;
          vtw[((size_t)(b * NH + h) * HDIM + d) * SEQ + s] = (_Float16)v;
        }
      }
    }
}

// ---------------------------------------------------------------------------
// Split-f16 O-projection GEMM: BM=128, BN=64, BK=32, 4 waves (2x2) of 64x32
// (4x2 frags), 3 MFMAs per frag pair.  Grid (16,32) = 512 blocks (2/CU).
// ---------------------------------------------------------------------------
__global__ __launch_bounds__(256) void ogemm_kernel(
    const _Float16* __restrict__ Ah, const _Float16* __restrict__ Al,
    const _Float16* __restrict__ Wh, const _Float16* __restrict__ Wl,
    const float* __restrict__ bias, float* __restrict__ out) {
  __shared__ _Float16 Ash[128][40];
  __shared__ _Float16 Asl[128][40];
  __shared__ _Float16 Bsh[64][40];
  __shared__ _Float16 Bsl[64][40];
  const int t = threadIdx.x;
  const int lane = t & 63;
  const int w = t >> 6;
  const int wm = w & 1, wn = w >> 1;
  const int fr = lane & 15;
  const int fk = (lane >> 4) * 8;
  const int m0 = blockIdx.y * 128, n0 = blockIdx.x * 64;

  f32x4 acc[4][2];
#pragma unroll
  for (int i = 0; i < 4; ++i)
#pragma unroll
    for (int j = 0; j < 2; ++j) acc[i][j] = (f32x4){0.f, 0.f, 0.f, 0.f};

  const int arow = t >> 1;
  const int ac = (t & 1) * 16;
  const int brow = t >> 2;
  const int bc = (t & 3) * 8;
  const _Float16* pAh = Ah + (size_t)(m0 + arow) * DIMD + ac;
  const _Float16* pAl = Al + (size_t)(m0 + arow) * DIMD + ac;
  const _Float16* pWh = Wh + (size_t)(n0 + brow) * DIMD + bc;
  const _Float16* pWl = Wl + (size_t)(n0 + brow) * DIMD + bc;

  for (int k0 = 0; k0 < DIMD; k0 += 32) {
    h8 rah0 = *(const h8*)(pAh + k0);
    h8 rah1 = *(const h8*)(pAh + k0 + 8);
    h8 ral0 = *(const h8*)(pAl + k0);
    h8 ral1 = *(const h8*)(pAl + k0 + 8);
    h8 rbh = *(const h8*)(pWh + k0);
    h8 rbl = *(const h8*)(pWl + k0);
    __syncthreads();
    *(h8*)&Ash[arow][ac] = rah0;
    *(h8*)&Ash[arow][ac + 8] = rah1;
    *(h8*)&Asl[arow][ac] = ral0;
    *(h8*)&Asl[arow][ac + 8] = ral1;
    *(h8*)&Bsh[brow][bc] = rbh;
    *(h8*)&Bsl[brow][bc] = rbl;
    __syncthreads();

    h8 ah[4], al[4], bh[2], bl[2];
#pragma unroll
    for (int mi = 0; mi < 4; ++mi) {
      ah[mi] = *(const h8*)&Ash[wm * 64 + mi * 16 + fr][fk];
      al[mi] = *(const h8*)&Asl[wm * 64 + mi * 16 + fr][fk];
    }
#pragma unroll
    for (int ni = 0; ni < 2; ++ni) {
      bh[ni] = *(const h8*)&Bsh[wn * 32 + ni * 16 + fr][fk];
      bl[ni] = *(const h8*)&Bsl[wn * 32 + ni * 16 + fr][fk];
    }
#pragma unroll
    for (int mi = 0; mi < 4; ++mi)
#pragma unroll
      for (int ni = 0; ni < 2; ++ni) {
        acc[mi][ni] = __builtin_amdgcn_mfma_f32_16x16x32_f16(
            ah[mi], bh[ni], acc[mi][ni], 0, 0, 0);
        acc[mi][ni] = __builtin_amdgcn_mfma_f32_16x16x32_f16(
            ah[mi], bl[ni], acc[mi][ni], 0, 0, 0);
        acc[mi][ni] = __builtin_amdgcn_mfma_f32_16x16x32_f16(
            al[mi], bh[ni], acc[mi][ni], 0, 0, 0);
      }
  }

#pragma unroll
  for (int mi = 0; mi < 4; ++mi)
#pragma unroll
    for (int ni = 0; ni < 2; ++ni) {
      const int col = n0 + wn * 32 + ni * 16 + fr;
      const float bsv = bias[col];
#pragma unroll
      for (int r = 0; r < 4; ++r) {
        const int row = m0 + wm * 64 + mi * 16 + (lane >> 4) * 4 + r;
        out[(size_t)row * DIMD + col] = acc[mi][ni][r] + bsv;
      }
    }
}

// ---------------------------------------------------------------------------
// f16 MFMA flash attention, swapped-QK^T / in-register-P, QBLK=64.
// Grid (S/64, B*H) = (32,32) = 1024 blocks (4/CU).  Wave owns 16 q-rows.
// ---------------------------------------------------------------------------
__global__ __launch_bounds__(256) void flash_kernel(
    const _Float16* __restrict__ qh, const _Float16* __restrict__ kh,
    const _Float16* __restrict__ vt, const _Float16* __restrict__ sg,
    _Float16* __restrict__ agh, _Float16* __restrict__ agl) {
  __shared__ _Float16 K_lds[4096];
  __shared__ _Float16 Vt_lds[4096];
  const int t = threadIdx.x;
  const int lane = t & 63;
  const int w = t >> 6;
  const int fr = lane & 15;
  const int g = lane >> 4;
  const int bh = blockIdx.y;
  const int q0 = blockIdx.x * 64;
  const size_t kvbase = (size_t)bh * (SEQ * HDIM);

  h8 qb[2];
  {
    const _Float16* qp =
        qh + kvbase + (size_t)(q0 + 16 * w + fr) * HDIM + 8 * g;
    qb[0] = *(const h8*)(qp);
    qb[1] = *(const h8*)(qp + 32);
  }

  f32x4 oacc[4];
  float m_i = -1e30f, l_i = 0.f;
#pragma unroll
  for (int df = 0; df < 4; ++df) oacc[df] = (f32x4){0.f, 0.f, 0.f, 0.f};

  const int srow = t >> 2;       // 0..63
  const int scb = (t & 3) * 16;  // 0,16,32,48
  const _Float16* kp = kh + kvbase;
  const _Float16* vp = vt + kvbase + (size_t)srow * SEQ;

  for (int j0 = 0; j0 < SEQ; j0 += 64) {
    h8 k0v = *(const h8*)(kp + (size_t)(j0 + srow) * HDIM + scb);
    h8 k1v = *(const h8*)(kp + (size_t)(j0 + srow) * HDIM + scb + 8);
    h8 v0v = *(const h8*)(vp + j0 + scb);
    h8 v1v = *(const h8*)(vp + j0 + scb + 8);
    __syncthreads();  // previous tile's frag reads complete
    *(h8*)&K_lds[SWE(srow, scb)] = k0v;
    *(h8*)&K_lds[SWE(srow, scb + 8)] = k1v;
    *(h8*)&Vt_lds[SWE(srow, scb)] = v0v;
    *(h8*)&Vt_lds[SWE(srow, scb + 8)] = v1v;
    __syncthreads();

    // S^T = K Q^T: sacc[nf] covers kv rows 16nf..16nf+15, q col fr.
    f32x4 sacc[4];
#pragma unroll
    for (int nf = 0; nf < 4; ++nf) sacc[nf] = (f32x4){0.f, 0.f, 0.f, 0.f};

    __builtin_amdgcn_s_setprio(1);
#pragma unroll
    for (int nf = 0; nf < 4; ++nf) {
      h8 ka0 = *(const h8*)&K_lds[SWE(16 * nf + fr, 8 * g)];
      h8 ka1 = *(const h8*)&K_lds[SWE(16 * nf + fr, 32 + 8 * g)];
      sacc[nf] =
          __builtin_amdgcn_mfma_f32_16x16x32_f16(ka0, qb[0], sacc[nf], 0, 0, 0);
      sacc[nf] =
          __builtin_amdgcn_mfma_f32_16x16x32_f16(ka1, qb[1], sacc[nf], 0, 0, 0);
    }
    __builtin_amdgcn_s_setprio(0);

    // In-register online softmax with defer-max (THR=8).
    float m0 = fmaxf(fmaxf(sacc[0][0], sacc[0][1]), sacc[0][2]);
    float m1 = fmaxf(fmaxf(sacc[0][3], sacc[1][0]), sacc[1][1]);
    float m2 = fmaxf(fmaxf(sacc[1][2], sacc[1][3]), sacc[2][0]);
    float m3 = fmaxf(fmaxf(sacc[2][1], sacc[2][2]), sacc[2][3]);
    float m4 = fmaxf(fmaxf(sacc[3][0], sacc[3][1]), sacc[3][2]);
    float mx =
        fmaxf(fmaxf(fmaxf(fmaxf(m0, m1), m2), fmaxf(m3, m4)), sacc[3][3]);
    mx = fmaxf(mx, __shfl_xor(mx, 16));
    mx = fmaxf(mx, __shfl_xor(mx, 32));
    const int allskip = __all(mx <= m_i + 8.0f);
    const float mn = allskip ? m_i : fmaxf(m_i, mx);
    float p[4][4];
    float rs = 0.f;
#pragma unroll
    for (int nf = 0; nf < 4; ++nf)
#pragma unroll
      for (int r = 0; r < 4; ++r) {
        p[nf][r] = __expf(sacc[nf][r] - mn);
        rs += p[nf][r];
      }
    rs += __shfl_xor(rs, 16);
    rs += __shfl_xor(rs, 32);
    if (allskip) {
      l_i += rs;
    } else {
      float f = __expf(m_i - mn);
      l_i = l_i * f + rs;
      m_i = mn;
      f32x4 fv = (f32x4){f, f, f, f};
#pragma unroll
      for (int df = 0; df < 4; ++df) oacc[df] *= fv;
    }
    // B-frag pack: pb[m2] elems = p[2m2][0..3], p[2m2+1][0..3]
    h8 pb[2];
#pragma unroll
    for (int m2 = 0; m2 < 2; ++m2) {
      union {
        h8 v;
        fp16x2 h[4];
      } u;
      u.h[0] = __builtin_amdgcn_cvt_pkrtz(p[2 * m2][0], p[2 * m2][1]);
      u.h[1] = __builtin_amdgcn_cvt_pkrtz(p[2 * m2][2], p[2 * m2][3]);
      u.h[2] = __builtin_amdgcn_cvt_pkrtz(p[2 * m2 + 1][0], p[2 * m2 + 1][1]);
      u.h[3] = __builtin_amdgcn_cvt_pkrtz(p[2 * m2 + 1][2], p[2 * m2 + 1][3]);
      pb[m2] = u.v;
    }

    // O^T += V^T P^T
    __builtin_amdgcn_s_setprio(1);
#pragma unroll
    for (int df = 0; df < 4; ++df) {
#pragma unroll
      for (int m2 = 0; m2 < 2; ++m2) {
        h4 vlo = *(const h4*)&Vt_lds[SWE(16 * df + fr, 32 * m2 + 4 * g)];
        h4 vhi = *(const h4*)&Vt_lds[SWE(16 * df + fr, 32 * m2 + 16 + 4 * g)];
        h8 va;
#pragma unroll
        for (int r = 0; r < 4; ++r) {
          va[r] = vlo[r];
          va[4 + r] = vhi[r];
        }
        oacc[df] =
            __builtin_amdgcn_mfma_f32_16x16x32_f16(va, pb[m2], oacc[df], 0, 0, 0);
      }
    }
    __builtin_amdgcn_s_setprio(0);
  }

  // Epilogue: lane holds O^T[d=16df+4g+r][q=q0+16w+fr].
  const int b = bh >> 4, h = bh & 15;
  const int qrow = q0 + 16 * w + fr;
  const float inv = 1.0f / l_i;
  const size_t obase = ((size_t)(b * SEQ + qrow)) * DIMD + h * HDIM;
#pragma unroll
  for (int df = 0; df < 4; ++df) {
    const int d0 = 16 * df + 4 * g;
    h4 gt = *(const h4*)&sg[obase + d0];
    h4 HI, LO;
#pragma unroll
    for (int r = 0; r < 4; ++r) {
      float val = oacc[df][r] * inv * (float)gt[r];
      _Float16 hi = (_Float16)val;
      HI[r] = hi;
      LO[r] = (_Float16)(val - (float)hi);
    }
    *(h4*)&agh[obase + d0] = HI;
    *(h4*)&agl[obase + d0] = LO;
  }
}

// ---------------------------------------------------------------------------
extern "C" void kernel_launch(void* const* d_in, const int* in_sizes, int n_in,
                              void* d_out, int out_size, void* d_ws,
                              size_t ws_size, hipStream_t stream) {
  const float* query = (const float*)d_in[0];
  const float* Wq = (const float*)d_in[1];
  const float* bq = (const float*)d_in[2];
  const float* Wk = (const float*)d_in[3];
  const float* bk = (const float*)d_in[4];
  const float* Wv = (const float*)d_in[5];
  const float* bv = (const float*)d_in[6];
  const float* Wo = (const float*)d_in[7];
  const float* bo = (const float*)d_in[8];
  float* out = (float*)d_out;

  float* fws = (float*)d_ws;
  float* sintab = fws;
  float* costab = fws + 65536;
  _Float16* Ah = (_Float16*)(fws + 131072);  // query f16 / later agh
  _Float16* Al = Ah + 4194304;               // later agl
  _Float16* Wqh = Al + 4194304;
  _Float16* Wkh = Wqh + 2097152;
  _Float16* Wvh = Wkh + 1048576;
  _Float16* Woh = Wvh + 1048576;
  _Float16* Wol = Woh + 1048576;
  _Float16* qw = Wol + 1048576;   // (B,H,S,64) q, roped, pre-scaled
  _Float16* kw = qw + 4194304;    // (B,H,S,64) k, roped
  _Float16* vtw = kw + 4194304;   // (B,H,64,S) v transposed
  _Float16* sg = vtw + 4194304;   // (B,S,D) sigmoid(gate)
  _Float16* agh = Ah;             // reuse after qkv gemm
  _Float16* agl = Al;

  rope_table_kernel<<<256, 256, 0, stream>>>(sintab, costab);
  convert_kernel<<<4096, 256, 0, stream>>>(query, Ah, 1048576);
  convert_kernel<<<2048, 256, 0, stream>>>(Wq, Wqh, 524288);
  convert_kernel<<<1024, 256, 0, stream>>>(Wk, Wkh, 262144);
  convert_kernel<<<1024, 256, 0, stream>>>(Wv, Wvh, 262144);
  split_kernel<<<1024, 256, 0, stream>>>(Wo, Woh, Wol, 262144);

  qkv_kernel<<<dim3(32, 32), 256, 0, stream>>>(Ah, Wqh, Wkh, Wvh, bq, bk, bv,
                                               qw, sg, kw, vtw, sintab, costab);

  flash_kernel<<<dim3(32, 32), 256, 0, stream>>>(qw, kw, vtw, sg, agh, agl);

  ogemm_kernel<<<dim3(16, 32), 256, 0, stream>>>(agh, agl, Woh, Wol, bo, out);
}

// Round 7
// 178.568 us; speedup vs baseline: 6.7229x; 1.1509x over previous
//
#include <hip/hip_runtime.h>
#include <math.h>

#define SEQ 2048
#define DIMD 1024
#define NH 16
#define HDIM 64

typedef _Float16 h8 __attribute__((ext_vector_type(8)));
typedef _Float16 h4 __attribute__((ext_vector_type(4)));
typedef __fp16 fp16x2 __attribute__((ext_vector_type(2)));
typedef float f32x4 __attribute__((ext_vector_type(4)));

// element-index swizzle for [*][64] f16 tiles (128B rows): XOR element bits
// 3-5 with (row&7).  Frag reads (16 lanes, same col, rows r..r+15) become
// 2 lanes per 16B slot = conflict-free; staged writes spread evenly.
__device__ __forceinline__ int SWE(int r, int c) {
  return ((r << 6) + c) ^ ((r & 7) << 3);
}

// ---------------------------------------------------------------------------
// Fused prep: RoPE table (double precision) + f32->f16 converts + Wo split.
// Range-dispatched single kernel, 9280 blocks.
// ---------------------------------------------------------------------------
#define R0 16384          // rope items (x4 idx each)
#define R1 (R0 + 1048576) // query f32x4
#define R2 (R1 + 524288)  // Wq
#define R3 (R2 + 262144)  // Wk
#define R4 (R3 + 262144)  // Wv
#define R5 (R4 + 262144)  // Wo (split)

__global__ void prep_kernel(const float* __restrict__ query,
                            const float* __restrict__ Wq,
                            const float* __restrict__ Wk,
                            const float* __restrict__ Wv,
                            const float* __restrict__ Wo,
                            _Float16* __restrict__ Ah,
                            _Float16* __restrict__ Wqh,
                            _Float16* __restrict__ Wkh,
                            _Float16* __restrict__ Wvh,
                            _Float16* __restrict__ Woh,
                            _Float16* __restrict__ Wol,
                            float* __restrict__ sintab,
                            float* __restrict__ costab) {
  int i = blockIdx.x * 256 + threadIdx.x;
  if (i < R0) {
#pragma unroll
    for (int j = 0; j < 4; ++j) {
      int idx = i * 4 + j;
      int tp = idx >> 5;
      int fi = idx & 31;
      double inv = pow(10000.0, -(double)(2 * fi) / 64.0);
      double a = (double)tp * inv;
      sintab[idx] = (float)sin(a);
      costab[idx] = (float)cos(a);
    }
    return;
  }
  const float* src;
  _Float16* dst;
  int k;
  if (i < R1) {
    k = i - R0; src = query; dst = Ah;
  } else if (i < R2) {
    k = i - R1; src = Wq; dst = Wqh;
  } else if (i < R3) {
    k = i - R2; src = Wk; dst = Wkh;
  } else if (i < R4) {
    k = i - R3; src = Wv; dst = Wvh;
  } else if (i < R5) {
    k = i - R4;
    float4 v = ((const float4*)Wo)[k];
    h4 H, L;
    H[0] = (_Float16)v.x; L[0] = (_Float16)(v.x - (float)H[0]);
    H[1] = (_Float16)v.y; L[1] = (_Float16)(v.y - (float)H[1]);
    H[2] = (_Float16)v.z; L[2] = (_Float16)(v.z - (float)H[2]);
    H[3] = (_Float16)v.w; L[3] = (_Float16)(v.w - (float)H[3]);
    ((h4*)Woh)[k] = H;
    ((h4*)Wol)[k] = L;
    return;
  } else {
    return;
  }
  float4 v = ((const float4*)src)[k];
  h4 H;
  H[0] = (_Float16)v.x;
  H[1] = (_Float16)v.y;
  H[2] = (_Float16)v.z;
  H[3] = (_Float16)v.w;
  ((h4*)dst)[k] = H;
}

// ---------------------------------------------------------------------------
// Fused QKV projection GEMM over concat N=4096 (q|gate 2048, k 1024, v 1024).
// Tile 128x128, BK=64, 2-phase reg-staged pipeline, SWE-swizzled LDS.
// 4 waves of 64x64 (4x4 frags of 16x16x32), grid 32x32 = 1024 blocks.
// ---------------------------------------------------------------------------
__global__ __launch_bounds__(256, 3) void qkv_kernel(
    const _Float16* __restrict__ Ah, const _Float16* __restrict__ Wqh,
    const _Float16* __restrict__ Wkh, const _Float16* __restrict__ Wvh,
    const float* __restrict__ bq, const float* __restrict__ bk,
    const float* __restrict__ bv, _Float16* __restrict__ qw,
    _Float16* __restrict__ sg, _Float16* __restrict__ kw,
    _Float16* __restrict__ vtw, const float* __restrict__ sintab,
    const float* __restrict__ costab) {
  __shared__ _Float16 Ash[8192];  // [128][64] swizzled
  __shared__ _Float16 Bsh[8192];
  const int t = threadIdx.x;
  const int lane = t & 63;
  const int w = t >> 6;
  const int wm = w & 1, wn = w >> 1;
  const int fr = lane & 15;
  const int g = lane >> 4;
  const int m0 = blockIdx.y * 128;
  const int n0 = blockIdx.x * 128;
  const int region = (n0 < 2048) ? 0 : (n0 < 3072 ? 1 : 2);
  const _Float16* Wb = region == 0   ? Wqh + (size_t)n0 * DIMD
                       : region == 1 ? Wkh + (size_t)(n0 - 2048) * DIMD
                                     : Wvh + (size_t)(n0 - 3072) * DIMD;
  const float* bias = region == 0   ? bq + n0
                      : region == 1 ? bk + (n0 - 2048)
                                    : bv + (n0 - 3072);

  f32x4 acc[4][4];
#pragma unroll
  for (int i = 0; i < 4; ++i)
#pragma unroll
    for (int j = 0; j < 4; ++j) acc[i][j] = (f32x4){0.f, 0.f, 0.f, 0.f};

  const int srow = t >> 1;       // 0..127
  const int sc = (t & 1) * 32;   // 0 or 32
  const _Float16* pA = Ah + (size_t)(m0 + srow) * DIMD + sc;
  const _Float16* pW = Wb + (size_t)srow * DIMD + sc;

  // prologue: stage tile 0 into registers
  h8 ra0 = *(const h8*)(pA);
  h8 ra1 = *(const h8*)(pA + 8);
  h8 ra2 = *(const h8*)(pA + 16);
  h8 ra3 = *(const h8*)(pA + 24);
  h8 rb0 = *(const h8*)(pW);
  h8 rb1 = *(const h8*)(pW + 8);
  h8 rb2 = *(const h8*)(pW + 16);
  h8 rb3 = *(const h8*)(pW + 24);

  for (int k0 = 0; k0 < DIMD; k0 += 64) {
    __syncthreads();  // prior frag reads done before overwrite
    *(h8*)&Ash[SWE(srow, sc + 0)] = ra0;
    *(h8*)&Ash[SWE(srow, sc + 8)] = ra1;
    *(h8*)&Ash[SWE(srow, sc + 16)] = ra2;
    *(h8*)&Ash[SWE(srow, sc + 24)] = ra3;
    *(h8*)&Bsh[SWE(srow, sc + 0)] = rb0;
    *(h8*)&Bsh[SWE(srow, sc + 8)] = rb1;
    *(h8*)&Bsh[SWE(srow, sc + 16)] = rb2;
    *(h8*)&Bsh[SWE(srow, sc + 24)] = rb3;
    __syncthreads();
    if (k0 + 64 < DIMD) {  // issue next tile's loads; fly under MFMA
      ra0 = *(const h8*)(pA + k0 + 64);
      ra1 = *(const h8*)(pA + k0 + 72);
      ra2 = *(const h8*)(pA + k0 + 80);
      ra3 = *(const h8*)(pA + k0 + 88);
      rb0 = *(const h8*)(pW + k0 + 64);
      rb1 = *(const h8*)(pW + k0 + 72);
      rb2 = *(const h8*)(pW + k0 + 80);
      rb3 = *(const h8*)(pW + k0 + 88);
    }
#pragma unroll
    for (int s = 0; s < 2; ++s) {
      h8 av[4], bv[4];
#pragma unroll
      for (int mi = 0; mi < 4; ++mi)
        av[mi] = *(const h8*)&Ash[SWE(wm * 64 + mi * 16 + fr, 8 * g + 32 * s)];
#pragma unroll
      for (int ni = 0; ni < 4; ++ni)
        bv[ni] = *(const h8*)&Bsh[SWE(wn * 64 + ni * 16 + fr, 8 * g + 32 * s)];
      __builtin_amdgcn_s_setprio(1);
#pragma unroll
      for (int mi = 0; mi < 4; ++mi)
#pragma unroll
        for (int ni = 0; ni < 4; ++ni)
          acc[mi][ni] = __builtin_amdgcn_mfma_f32_16x16x32_f16(
              av[mi], bv[ni], acc[mi][ni], 0, 0, 0);
      __builtin_amdgcn_s_setprio(0);
    }
  }

  // Epilogue. C/D layout: col = lane&15, row = (lane>>4)*4 + reg.
#pragma unroll
  for (int mi = 0; mi < 4; ++mi)
#pragma unroll
    for (int ni = 0; ni < 4; ++ni) {
      const int cl = wn * 64 + ni * 16 + fr;  // col within tile
      const float bsv = bias[cl];
#pragma unroll
      for (int r = 0; r < 4; ++r) {
        const int row = m0 + wm * 64 + mi * 16 + (lane >> 4) * 4 + r;
        float v = acc[mi][ni][r] + bsv;
        const int b = row >> 11;
        const int s = row & (SEQ - 1);
        if (region == 0) {
          const int h = n0 >> 7;
          const int d = cl & 63;
          if (wn == 0) {  // q: rope + SCALE
            float vp = __shfl_xor(v, 1);
            const int pi = s * 32 + (d >> 1);
            float sn = sintab[pi], cs = costab[pi];
            float rv = (d & 1) ? (vp * sn + v * cs) : (v * cs - vp * sn);
            rv *= 0.125f;
            qw[((size_t)(b * NH + h) * SEQ + s) * HDIM + d] = (_Float16)rv;
          } else {  // gate: sigmoid -> (B,S,D)
            float gv = 1.0f / (1.0f + __expf(-v));
            sg[((size_t)(b * SEQ + s)) * DIMD + h * HDIM + d] = (_Float16)gv;
          }
        } else if (region == 1) {
          const int kc = (n0 - 2048) + cl;
          const int h = kc >> 6, d = kc & 63;
          float vp = __shfl_xor(v, 1);
          const int pi = s * 32 + (d >> 1);
          float sn = sintab[pi], cs = costab[pi];
          float rv = (d & 1) ? (vp * sn + v * cs) : (v * cs - vp * sn);
          kw[((size_t)(b * NH + h) * SEQ + s) * HDIM + d] = (_Float16)rv;
        } else {
          const int vc = (n0 - 3072) + cl;
          const int h = vc >> 6, d = vc & 63;
          vtw[((size_t)(b * NH + h) * HDIM + d) * SEQ + s] = (_Float16)v;
        }
      }
    }
}

// ---------------------------------------------------------------------------
// Split-f16 O-projection GEMM: BM=128, BN=64, BK=64, 2-phase reg-staged,
// SWE-swizzled LDS, 4 waves (2x2) of 64x32, 3 MFMAs per frag pair.
// Grid (16,32) = 512 blocks.
// ---------------------------------------------------------------------------
__global__ __launch_bounds__(256, 2) void ogemm_kernel(
    const _Float16* __restrict__ Ah, const _Float16* __restrict__ Al,
    const _Float16* __restrict__ Wh, const _Float16* __restrict__ Wl,
    const float* __restrict__ bias, float* __restrict__ out) {
  __shared__ _Float16 Ash[8192];  // [128][64] swizzled
  __shared__ _Float16 Asl[8192];
  __shared__ _Float16 Bsh[4096];  // [64][64] swizzled
  __shared__ _Float16 Bsl[4096];
  const int t = threadIdx.x;
  const int lane = t & 63;
  const int w = t >> 6;
  const int wm = w & 1, wn = w >> 1;
  const int fr = lane & 15;
  const int g = lane >> 4;
  const int m0 = blockIdx.y * 128, n0 = blockIdx.x * 64;

  f32x4 acc[4][2];
#pragma unroll
  for (int i = 0; i < 4; ++i)
#pragma unroll
    for (int j = 0; j < 2; ++j) acc[i][j] = (f32x4){0.f, 0.f, 0.f, 0.f};

  const int arow = t >> 1;      // 0..127
  const int ac = (t & 1) * 32;
  const int brow = t >> 2;      // 0..63
  const int bc = (t & 3) * 16;
  const _Float16* pAh = Ah + (size_t)(m0 + arow) * DIMD + ac;
  const _Float16* pAl = Al + (size_t)(m0 + arow) * DIMD + ac;
  const _Float16* pWh = Wh + (size_t)(n0 + brow) * DIMD + bc;
  const _Float16* pWl = Wl + (size_t)(n0 + brow) * DIMD + bc;

  h8 rah0 = *(const h8*)(pAh);
  h8 rah1 = *(const h8*)(pAh + 8);
  h8 rah2 = *(const h8*)(pAh + 16);
  h8 rah3 = *(const h8*)(pAh + 24);
  h8 ral0 = *(const h8*)(pAl);
  h8 ral1 = *(const h8*)(pAl + 8);
  h8 ral2 = *(const h8*)(pAl + 16);
  h8 ral3 = *(const h8*)(pAl + 24);
  h8 rbh0 = *(const h8*)(pWh);
  h8 rbh1 = *(const h8*)(pWh + 8);
  h8 rbl0 = *(const h8*)(pWl);
  h8 rbl1 = *(const h8*)(pWl + 8);

  for (int k0 = 0; k0 < DIMD; k0 += 64) {
    __syncthreads();
    *(h8*)&Ash[SWE(arow, ac + 0)] = rah0;
    *(h8*)&Ash[SWE(arow, ac + 8)] = rah1;
    *(h8*)&Ash[SWE(arow, ac + 16)] = rah2;
    *(h8*)&Ash[SWE(arow, ac + 24)] = rah3;
    *(h8*)&Asl[SWE(arow, ac + 0)] = ral0;
    *(h8*)&Asl[SWE(arow, ac + 8)] = ral1;
    *(h8*)&Asl[SWE(arow, ac + 16)] = ral2;
    *(h8*)&Asl[SWE(arow, ac + 24)] = ral3;
    *(h8*)&Bsh[SWE(brow, bc + 0)] = rbh0;
    *(h8*)&Bsh[SWE(brow, bc + 8)] = rbh1;
    *(h8*)&Bsl[SWE(brow, bc + 0)] = rbl0;
    *(h8*)&Bsl[SWE(brow, bc + 8)] = rbl1;
    __syncthreads();
    if (k0 + 64 < DIMD) {
      rah0 = *(const h8*)(pAh + k0 + 64);
      rah1 = *(const h8*)(pAh + k0 + 72);
      rah2 = *(const h8*)(pAh + k0 + 80);
      rah3 = *(const h8*)(pAh + k0 + 88);
      ral0 = *(const h8*)(pAl + k0 + 64);
      ral1 = *(const h8*)(pAl + k0 + 72);
      ral2 = *(const h8*)(pAl + k0 + 80);
      ral3 = *(const h8*)(pAl + k0 + 88);
      rbh0 = *(const h8*)(pWh + k0 + 64);
      rbh1 = *(const h8*)(pWh + k0 + 72);
      rbl0 = *(const h8*)(pWl + k0 + 64);
      rbl1 = *(const h8*)(pWl + k0 + 72);
    }
#pragma unroll
    for (int s = 0; s < 2; ++s) {
      h8 ahv[4], alv[4], bhv[2], blv[2];
#pragma unroll
      for (int mi = 0; mi < 4; ++mi) {
        ahv[mi] = *(const h8*)&Ash[SWE(wm * 64 + mi * 16 + fr, 8 * g + 32 * s)];
        alv[mi] = *(const h8*)&Asl[SWE(wm * 64 + mi * 16 + fr, 8 * g + 32 * s)];
      }
#pragma unroll
      for (int ni = 0; ni < 2; ++ni) {
        bhv[ni] = *(const h8*)&Bsh[SWE(wn * 32 + ni * 16 + fr, 8 * g + 32 * s)];
        blv[ni] = *(const h8*)&Bsl[SWE(wn * 32 + ni * 16 + fr, 8 * g + 32 * s)];
      }
      __builtin_amdgcn_s_setprio(1);
#pragma unroll
      for (int mi = 0; mi < 4; ++mi)
#pragma unroll
        for (int ni = 0; ni < 2; ++ni) {
          acc[mi][ni] = __builtin_amdgcn_mfma_f32_16x16x32_f16(
              ahv[mi], bhv[ni], acc[mi][ni], 0, 0, 0);
          acc[mi][ni] = __builtin_amdgcn_mfma_f32_16x16x32_f16(
              ahv[mi], blv[ni], acc[mi][ni], 0, 0, 0);
          acc[mi][ni] = __builtin_amdgcn_mfma_f32_16x16x32_f16(
              alv[mi], bhv[ni], acc[mi][ni], 0, 0, 0);
        }
      __builtin_amdgcn_s_setprio(0);
    }
  }

#pragma unroll
  for (int mi = 0; mi < 4; ++mi)
#pragma unroll
    for (int ni = 0; ni < 2; ++ni) {
      const int col = n0 + wn * 32 + ni * 16 + fr;
      const float bsv = bias[col];
#pragma unroll
      for (int r = 0; r < 4; ++r) {
        const int row = m0 + wm * 64 + mi * 16 + (lane >> 4) * 4 + r;
        out[(size_t)row * DIMD + col] = acc[mi][ni][r] + bsv;
      }
    }
}

// ---------------------------------------------------------------------------
// f16 MFMA flash attention, swapped-QK^T / in-register-P, QBLK=64.
// Grid (S/64, B*H) = (32,32) = 1024 blocks.  Wave owns 16 q-rows.
// (unchanged from round 6)
// ---------------------------------------------------------------------------
__global__ __launch_bounds__(256) void flash_kernel(
    const _Float16* __restrict__ qh, const _Float16* __restrict__ kh,
    const _Float16* __restrict__ vt, const _Float16* __restrict__ sg,
    _Float16* __restrict__ agh, _Float16* __restrict__ agl) {
  __shared__ _Float16 K_lds[4096];
  __shared__ _Float16 Vt_lds[4096];
  const int t = threadIdx.x;
  const int lane = t & 63;
  const int w = t >> 6;
  const int fr = lane & 15;
  const int g = lane >> 4;
  const int bh = blockIdx.y;
  const int q0 = blockIdx.x * 64;
  const size_t kvbase = (size_t)bh * (SEQ * HDIM);

  h8 qb[2];
  {
    const _Float16* qp =
        qh + kvbase + (size_t)(q0 + 16 * w + fr) * HDIM + 8 * g;
    qb[0] = *(const h8*)(qp);
    qb[1] = *(const h8*)(qp + 32);
  }

  f32x4 oacc[4];
  float m_i = -1e30f, l_i = 0.f;
#pragma unroll
  for (int df = 0; df < 4; ++df) oacc[df] = (f32x4){0.f, 0.f, 0.f, 0.f};

  const int srow = t >> 2;       // 0..63
  const int scb = (t & 3) * 16;  // 0,16,32,48
  const _Float16* kp = kh + kvbase;
  const _Float16* vp = vt + kvbase + (size_t)srow * SEQ;

  for (int j0 = 0; j0 < SEQ; j0 += 64) {
    h8 k0v = *(const h8*)(kp + (size_t)(j0 + srow) * HDIM + scb);
    h8 k1v = *(const h8*)(kp + (size_t)(j0 + srow) * HDIM + scb + 8);
    h8 v0v = *(const h8*)(vp + j0 + scb);
    h8 v1v = *(const h8*)(vp + j0 + scb + 8);
    __syncthreads();  // previous tile's frag reads complete
    *(h8*)&K_lds[SWE(srow, scb)] = k0v;
    *(h8*)&K_lds[SWE(srow, scb + 8)] = k1v;
    *(h8*)&Vt_lds[SWE(srow, scb)] = v0v;
    *(h8*)&Vt_lds[SWE(srow, scb + 8)] = v1v;
    __syncthreads();

    // S^T = K Q^T: sacc[nf] covers kv rows 16nf..16nf+15, q col fr.
    f32x4 sacc[4];
#pragma unroll
    for (int nf = 0; nf < 4; ++nf) sacc[nf] = (f32x4){0.f, 0.f, 0.f, 0.f};

    __builtin_amdgcn_s_setprio(1);
#pragma unroll
    for (int nf = 0; nf < 4; ++nf) {
      h8 ka0 = *(const h8*)&K_lds[SWE(16 * nf + fr, 8 * g)];
      h8 ka1 = *(const h8*)&K_lds[SWE(16 * nf + fr, 32 + 8 * g)];
      sacc[nf] =
          __builtin_amdgcn_mfma_f32_16x16x32_f16(ka0, qb[0], sacc[nf], 0, 0, 0);
      sacc[nf] =
          __builtin_amdgcn_mfma_f32_16x16x32_f16(ka1, qb[1], sacc[nf], 0, 0, 0);
    }
    __builtin_amdgcn_s_setprio(0);

    // In-register online softmax with defer-max (THR=8).
    float m0 = fmaxf(fmaxf(sacc[0][0], sacc[0][1]), sacc[0][2]);
    float m1 = fmaxf(fmaxf(sacc[0][3], sacc[1][0]), sacc[1][1]);
    float m2 = fmaxf(fmaxf(sacc[1][2], sacc[1][3]), sacc[2][0]);
    float m3 = fmaxf(fmaxf(sacc[2][1], sacc[2][2]), sacc[2][3]);
    float m4 = fmaxf(fmaxf(sacc[3][0], sacc[3][1]), sacc[3][2]);
    float mx =
        fmaxf(fmaxf(fmaxf(fmaxf(m0, m1), m2), fmaxf(m3, m4)), sacc[3][3]);
    mx = fmaxf(mx, __shfl_xor(mx, 16));
    mx = fmaxf(mx, __shfl_xor(mx, 32));
    const int allskip = __all(mx <= m_i + 8.0f);
    const float mn = allskip ? m_i : fmaxf(m_i, mx);
    float p[4][4];
    float rs = 0.f;
#pragma unroll
    for (int nf = 0; nf < 4; ++nf)
#pragma unroll
      for (int r = 0; r < 4; ++r) {
        p[nf][r] = __expf(sacc[nf][r] - mn);
        rs += p[nf][r];
      }
    rs += __shfl_xor(rs, 16);
    rs += __shfl_xor(rs, 32);
    if (allskip) {
      l_i += rs;
    } else {
      float f = __expf(m_i - mn);
      l_i = l_i * f + rs;
      m_i = mn;
      f32x4 fv = (f32x4){f, f, f, f};
#pragma unroll
      for (int df = 0; df < 4; ++df) oacc[df] *= fv;
    }
    // B-frag pack: pb[m2] elems = p[2m2][0..3], p[2m2+1][0..3]
    h8 pb[2];
#pragma unroll
    for (int m2 = 0; m2 < 2; ++m2) {
      union {
        h8 v;
        fp16x2 h[4];
      } u;
      u.h[0] = __builtin_amdgcn_cvt_pkrtz(p[2 * m2][0], p[2 * m2][1]);
      u.h[1] = __builtin_amdgcn_cvt_pkrtz(p[2 * m2][2], p[2 * m2][3]);
      u.h[2] = __builtin_amdgcn_cvt_pkrtz(p[2 * m2 + 1][0], p[2 * m2 + 1][1]);
      u.h[3] = __builtin_amdgcn_cvt_pkrtz(p[2 * m2 + 1][2], p[2 * m2 + 1][3]);
      pb[m2] = u.v;
    }

    // O^T += V^T P^T
    __builtin_amdgcn_s_setprio(1);
#pragma unroll
    for (int df = 0; df < 4; ++df) {
#pragma unroll
      for (int m2 = 0; m2 < 2; ++m2) {
        h4 vlo = *(const h4*)&Vt_lds[SWE(16 * df + fr, 32 * m2 + 4 * g)];
        h4 vhi = *(const h4*)&Vt_lds[SWE(16 * df + fr, 32 * m2 + 16 + 4 * g)];
        h8 va;
#pragma unroll
        for (int r = 0; r < 4; ++r) {
          va[r] = vlo[r];
          va[4 + r] = vhi[r];
        }
        oacc[df] =
            __builtin_amdgcn_mfma_f32_16x16x32_f16(va, pb[m2], oacc[df], 0, 0, 0);
      }
    }
    __builtin_amdgcn_s_setprio(0);
  }

  // Epilogue: lane holds O^T[d=16df+4g+r][q=q0+16w+fr].
  const int b = bh >> 4, h = bh & 15;
  const int qrow = q0 + 16 * w + fr;
  const float inv = 1.0f / l_i;
  const size_t obase = ((size_t)(b * SEQ + qrow)) * DIMD + h * HDIM;
#pragma unroll
  for (int df = 0; df < 4; ++df) {
    const int d0 = 16 * df + 4 * g;
    h4 gt = *(const h4*)&sg[obase + d0];
    h4 HI, LO;
#pragma unroll
    for (int r = 0; r < 4; ++r) {
      float val = oacc[df][r] * inv * (float)gt[r];
      _Float16 hi = (_Float16)val;
      HI[r] = hi;
      LO[r] = (_Float16)(val - (float)hi);
    }
    *(h4*)&agh[obase + d0] = HI;
    *(h4*)&agl[obase + d0] = LO;
  }
}

// ---------------------------------------------------------------------------
extern "C" void kernel_launch(void* const* d_in, const int* in_sizes, int n_in,
                              void* d_out, int out_size, void* d_ws,
                              size_t ws_size, hipStream_t stream) {
  const float* query = (const float*)d_in[0];
  const float* Wq = (const float*)d_in[1];
  const float* bq = (const float*)d_in[2];
  const float* Wk = (const float*)d_in[3];
  const float* bk = (const float*)d_in[4];
  const float* Wv = (const float*)d_in[5];
  const float* bv = (const float*)d_in[6];
  const float* Wo = (const float*)d_in[7];
  const float* bo = (const float*)d_in[8];
  float* out = (float*)d_out;

  float* fws = (float*)d_ws;
  float* sintab = fws;
  float* costab = fws + 65536;
  _Float16* Ah = (_Float16*)(fws + 131072);  // query f16 / later agh
  _Float16* Al = Ah + 4194304;               // later agl
  _Float16* Wqh = Al + 4194304;
  _Float16* Wkh = Wqh + 2097152;
  _Float16* Wvh = Wkh + 1048576;
  _Float16* Woh = Wvh + 1048576;
  _Float16* Wol = Woh + 1048576;
  _Float16* qw = Wol + 1048576;   // (B,H,S,64) q, roped, pre-scaled
  _Float16* kw = qw + 4194304;    // (B,H,S,64) k, roped
  _Float16* vtw = kw + 4194304;   // (B,H,64,S) v transposed
  _Float16* sg = vtw + 4194304;   // (B,S,D) sigmoid(gate)
  _Float16* agh = Ah;             // reuse after qkv gemm
  _Float16* agl = Al;

  prep_kernel<<<9280, 256, 0, stream>>>(query, Wq, Wk, Wv, Wo, Ah, Wqh, Wkh,
                                        Wvh, Woh, Wol, sintab, costab);

  qkv_kernel<<<dim3(32, 32), 256, 0, stream>>>(Ah, Wqh, Wkh, Wvh, bq, bk, bv,
                                               qw, sg, kw, vtw, sintab, costab);

  flash_kernel<<<dim3(32, 32), 256, 0, stream>>>(qw, kw, vtw, sg, agh, agl);

  ogemm_kernel<<<dim3(16, 32), 256, 0, stream>>>(agh, agl, Woh, Wol, bo, out);
}

// Round 8
// 157.164 us; speedup vs baseline: 7.6385x; 1.1362x over previous
//
#include <hip/hip_runtime.h>
#include <math.h>

#define SEQ 2048
#define DIMD 1024
#define NH 16
#define HDIM 64

typedef _Float16 h8 __attribute__((ext_vector_type(8)));
typedef _Float16 h4 __attribute__((ext_vector_type(4)));
typedef __fp16 fp16x2 __attribute__((ext_vector_type(2)));
typedef float f32x4 __attribute__((ext_vector_type(4)));

typedef const __attribute__((address_space(1))) void* gas_t;
typedef __attribute__((address_space(3))) void* las_t;

// element-index swizzle for [*][64] f16 tiles (128B rows): XOR element bits
// 3-5 with (row&7).  Permutes 16B chunks within a row; chunk-contiguous.
__device__ __forceinline__ int SWE(int r, int c) {
  return ((r << 6) + c) ^ ((r & 7) << 3);
}

// ---------------------------------------------------------------------------
// Fused prep: RoPE table (double precision) + f32->f16 converts.
// ---------------------------------------------------------------------------
#define R0 16384           // rope items (x4 idx each)
#define R1 (R0 + 1048576)  // query f32x4
#define R2 (R1 + 524288)   // Wq
#define R3 (R2 + 262144)   // Wk
#define R4 (R3 + 262144)   // Wv
#define R5 (R4 + 262144)   // Wo

__global__ void prep_kernel(const float* __restrict__ query,
                            const float* __restrict__ Wq,
                            const float* __restrict__ Wk,
                            const float* __restrict__ Wv,
                            const float* __restrict__ Wo,
                            _Float16* __restrict__ Ah,
                            _Float16* __restrict__ Wqh,
                            _Float16* __restrict__ Wkh,
                            _Float16* __restrict__ Wvh,
                            _Float16* __restrict__ Woh,
                            float* __restrict__ sintab,
                            float* __restrict__ costab) {
  int i = blockIdx.x * 256 + threadIdx.x;
  if (i < R0) {
#pragma unroll
    for (int j = 0; j < 4; ++j) {
      int idx = i * 4 + j;
      int tp = idx >> 5;
      int fi = idx & 31;
      double inv = pow(10000.0, -(double)(2 * fi) / 64.0);
      double a = (double)tp * inv;
      sintab[idx] = (float)sin(a);
      costab[idx] = (float)cos(a);
    }
    return;
  }
  const float* src;
  _Float16* dst;
  int k;
  if (i < R1) {
    k = i - R0; src = query; dst = Ah;
  } else if (i < R2) {
    k = i - R1; src = Wq; dst = Wqh;
  } else if (i < R3) {
    k = i - R2; src = Wk; dst = Wkh;
  } else if (i < R4) {
    k = i - R3; src = Wv; dst = Wvh;
  } else if (i < R5) {
    k = i - R4; src = Wo; dst = Woh;
  } else {
    return;
  }
  float4 v = ((const float4*)src)[k];
  h4 H;
  H[0] = (_Float16)v.x;
  H[1] = (_Float16)v.y;
  H[2] = (_Float16)v.z;
  H[3] = (_Float16)v.w;
  ((h4*)dst)[k] = H;
}

// ---------------------------------------------------------------------------
// Fused QKV projection GEMM, concat N=4096.  Tile 128x128, BK=64, dbuf LDS
// staged via global_load_lds with pre-swizzled per-lane source (SWE layout),
// counted vmcnt pipeline (never 0 mid-loop), raw s_barrier.  4 waves of
// 64x64.  Grid flat 1024, XCD-chunked swizzle.
// ---------------------------------------------------------------------------
__global__ __launch_bounds__(256) void qkv_kernel(
    const _Float16* __restrict__ Ah, const _Float16* __restrict__ Wqh,
    const _Float16* __restrict__ Wkh, const _Float16* __restrict__ Wvh,
    const float* __restrict__ bq, const float* __restrict__ bk,
    const float* __restrict__ bv, _Float16* __restrict__ qw,
    _Float16* __restrict__ sg, _Float16* __restrict__ kw,
    _Float16* __restrict__ vtw, const float* __restrict__ sintab,
    const float* __restrict__ costab) {
  __shared__ _Float16 Abuf[2][8192];
  __shared__ _Float16 Bbuf[2][8192];
  const int t = threadIdx.x;
  const int lane = t & 63;
  const int w = t >> 6;
  const int wm = w & 1, wn = w >> 1;
  const int fr = lane & 15;
  const int g = lane >> 4;
  const int flat = blockIdx.x;                    // 1024 blocks
  const int swz = (flat & 7) * 128 + (flat >> 3); // XCD-contiguous chunks
  const int m0 = (swz >> 5) * 128;
  const int n0 = (swz & 31) * 128;
  const int region = (n0 < 2048) ? 0 : (n0 < 3072 ? 1 : 2);
  const _Float16* Wb = region == 0   ? Wqh + (size_t)n0 * DIMD
                       : region == 1 ? Wkh + (size_t)(n0 - 2048) * DIMD
                                     : Wvh + (size_t)(n0 - 3072) * DIMD;
  const float* bias = region == 0   ? bq + n0
                      : region == 1 ? bk + (n0 - 2048)
                                    : bv + (n0 - 3072);

  f32x4 acc[4][4];
#pragma unroll
  for (int i = 0; i < 4; ++i)
#pragma unroll
    for (int j = 0; j < 4; ++j) acc[i][j] = (f32x4){0.f, 0.f, 0.f, 0.f};

  // staging source: lane L reads 16B of row (base + L>>3), chunk (L&7)^(L>>3)
  const int rsub = lane >> 3;
  const int csw = ((lane & 7) ^ rsub) << 3;
  const _Float16* gA = Ah + (size_t)(m0 + w * 32 + rsub) * DIMD + csw;
  const _Float16* gB = Wb + (size_t)(w * 32 + rsub) * DIMD + csw;
  const int ldsb = w * 2048;

  auto stage = [&](int kt, int pb) {
#pragma unroll
    for (int i = 0; i < 4; ++i) {
      __builtin_amdgcn_global_load_lds(
          (gas_t)(gA + (size_t)i * 8 * DIMD + kt * 64),
          (las_t)&Abuf[pb][ldsb + i * 512], 16, 0, 0);
      __builtin_amdgcn_global_load_lds(
          (gas_t)(gB + (size_t)i * 8 * DIMD + kt * 64),
          (las_t)&Bbuf[pb][ldsb + i * 512], 16, 0, 0);
    }
  };

  stage(0, 0);
  for (int kt = 0; kt < 16; ++kt) {
    const int pb = kt & 1;
    if (kt < 15) {
      stage(kt + 1, pb ^ 1);
      asm volatile("s_waitcnt vmcnt(8)" ::: "memory");
    } else {
      asm volatile("s_waitcnt vmcnt(0)" ::: "memory");
    }
    __builtin_amdgcn_sched_barrier(0);
    __builtin_amdgcn_s_barrier();
#pragma unroll
    for (int s = 0; s < 2; ++s) {
      h8 av[4], bv[4];
#pragma unroll
      for (int mi = 0; mi < 4; ++mi)
        av[mi] = *(const h8*)&Abuf[pb][SWE(wm * 64 + mi * 16 + fr, 8 * g + 32 * s)];
#pragma unroll
      for (int ni = 0; ni < 4; ++ni)
        bv[ni] = *(const h8*)&Bbuf[pb][SWE(wn * 64 + ni * 16 + fr, 8 * g + 32 * s)];
      __builtin_amdgcn_s_setprio(1);
#pragma unroll
      for (int mi = 0; mi < 4; ++mi)
#pragma unroll
        for (int ni = 0; ni < 4; ++ni)
          acc[mi][ni] = __builtin_amdgcn_mfma_f32_16x16x32_f16(
              av[mi], bv[ni], acc[mi][ni], 0, 0, 0);
      __builtin_amdgcn_s_setprio(0);
    }
    __builtin_amdgcn_s_barrier();
  }

  // Epilogue. C/D layout: col = lane&15, row = (lane>>4)*4 + reg.
#pragma unroll
  for (int mi = 0; mi < 4; ++mi)
#pragma unroll
    for (int ni = 0; ni < 4; ++ni) {
      const int cl = wn * 64 + ni * 16 + fr;
      const float bsv = bias[cl];
      if (region == 2) {  // V: vectorized h4 store (4 consecutive s)
        const int vc = (n0 - 3072) + cl;
        const int h = vc >> 6, d = vc & 63;
        const int row0 = m0 + wm * 64 + mi * 16 + g * 4;
        const int b = row0 >> 11;
        const int s0 = row0 & (SEQ - 1);
        h4 vv;
#pragma unroll
        for (int r = 0; r < 4; ++r) vv[r] = (_Float16)(acc[mi][ni][r] + bsv);
        *(h4*)&vtw[((size_t)(b * NH + h) * HDIM + d) * SEQ + s0] = vv;
        continue;
      }
#pragma unroll
      for (int r = 0; r < 4; ++r) {
        const int row = m0 + wm * 64 + mi * 16 + g * 4 + r;
        float v = acc[mi][ni][r] + bsv;
        const int b = row >> 11;
        const int s = row & (SEQ - 1);
        if (region == 0) {
          const int h = n0 >> 7;
          const int d = cl & 63;
          if (wn == 0) {  // q: rope + SCALE
            float vp = __shfl_xor(v, 1);
            const int pi = s * 32 + (d >> 1);
            float sn = sintab[pi], cs = costab[pi];
            float rv = (d & 1) ? (vp * sn + v * cs) : (v * cs - vp * sn);
            rv *= 0.125f;
            qw[((size_t)(b * NH + h) * SEQ + s) * HDIM + d] = (_Float16)rv;
          } else {  // gate: sigmoid -> (B,S,D)
            float gv = 1.0f / (1.0f + __expf(-v));
            sg[((size_t)(b * SEQ + s)) * DIMD + h * HDIM + d] = (_Float16)gv;
          }
        } else {  // region 1: K rope
          const int kc = (n0 - 2048) + cl;
          const int h = kc >> 6, d = kc & 63;
          float vp = __shfl_xor(v, 1);
          const int pi = s * 32 + (d >> 1);
          float sn = sintab[pi], cs = costab[pi];
          float rv = (d & 1) ? (vp * sn + v * cs) : (v * cs - vp * sn);
          kw[((size_t)(b * NH + h) * SEQ + s) * HDIM + d] = (_Float16)rv;
        }
      }
    }
}

// ---------------------------------------------------------------------------
// O-projection GEMM (plain f16): BM=128, BN=64, BK=64, same gload_lds
// pipeline.  4 waves (2x2) of 64x32.  Grid flat 512, XCD swizzle.
// ---------------------------------------------------------------------------
__global__ __launch_bounds__(256) void ogemm_kernel(
    const _Float16* __restrict__ ag, const _Float16* __restrict__ Woh,
    const float* __restrict__ bias, float* __restrict__ out) {
  __shared__ _Float16 Abuf[2][8192];
  __shared__ _Float16 Bbuf[2][4096];
  const int t = threadIdx.x;
  const int lane = t & 63;
  const int w = t >> 6;
  const int wm = w & 1, wn = w >> 1;
  const int fr = lane & 15;
  const int g = lane >> 4;
  const int flat = blockIdx.x;                   // 512 blocks
  const int swz = (flat & 7) * 64 + (flat >> 3);
  const int m0 = (swz >> 4) * 128;
  const int n0 = (swz & 15) * 64;

  f32x4 acc[4][2];
#pragma unroll
  for (int i = 0; i < 4; ++i)
#pragma unroll
    for (int j = 0; j < 2; ++j) acc[i][j] = (f32x4){0.f, 0.f, 0.f, 0.f};

  const int rsub = lane >> 3;
  const int csw = ((lane & 7) ^ rsub) << 3;
  const _Float16* gA = ag + (size_t)(m0 + w * 32 + rsub) * DIMD + csw;
  const _Float16* gB = Woh + (size_t)(n0 + w * 16 + rsub) * DIMD + csw;
  const int ldsbA = w * 2048;
  const int ldsbB = w * 1024;

  auto stage = [&](int kt, int pb) {
#pragma unroll
    for (int i = 0; i < 4; ++i)
      __builtin_amdgcn_global_load_lds(
          (gas_t)(gA + (size_t)i * 8 * DIMD + kt * 64),
          (las_t)&Abuf[pb][ldsbA + i * 512], 16, 0, 0);
#pragma unroll
    for (int i = 0; i < 2; ++i)
      __builtin_amdgcn_global_load_lds(
          (gas_t)(gB + (size_t)i * 8 * DIMD + kt * 64),
          (las_t)&Bbuf[pb][ldsbB + i * 512], 16, 0, 0);
  };

  stage(0, 0);
  for (int kt = 0; kt < 16; ++kt) {
    const int pb = kt & 1;
    if (kt < 15) {
      stage(kt + 1, pb ^ 1);
      asm volatile("s_waitcnt vmcnt(6)" ::: "memory");
    } else {
      asm volatile("s_waitcnt vmcnt(0)" ::: "memory");
    }
    __builtin_amdgcn_sched_barrier(0);
    __builtin_amdgcn_s_barrier();
#pragma unroll
    for (int s = 0; s < 2; ++s) {
      h8 av[4], bv[2];
#pragma unroll
      for (int mi = 0; mi < 4; ++mi)
        av[mi] = *(const h8*)&Abuf[pb][SWE(wm * 64 + mi * 16 + fr, 8 * g + 32 * s)];
#pragma unroll
      for (int ni = 0; ni < 2; ++ni)
        bv[ni] = *(const h8*)&Bbuf[pb][SWE(wn * 32 + ni * 16 + fr, 8 * g + 32 * s)];
      __builtin_amdgcn_s_setprio(1);
#pragma unroll
      for (int mi = 0; mi < 4; ++mi)
#pragma unroll
        for (int ni = 0; ni < 2; ++ni)
          acc[mi][ni] = __builtin_amdgcn_mfma_f32_16x16x32_f16(
              av[mi], bv[ni], acc[mi][ni], 0, 0, 0);
      __builtin_amdgcn_s_setprio(0);
    }
    __builtin_amdgcn_s_barrier();
  }

#pragma unroll
  for (int mi = 0; mi < 4; ++mi)
#pragma unroll
    for (int ni = 0; ni < 2; ++ni) {
      const int col = n0 + wn * 32 + ni * 16 + fr;
      const float bsv = bias[col];
#pragma unroll
      for (int r = 0; r < 4; ++r) {
        const int row = m0 + wm * 64 + mi * 16 + g * 4 + r;
        out[(size_t)row * DIMD + col] = acc[mi][ni][r] + bsv;
      }
    }
}

// ---------------------------------------------------------------------------
// f16 MFMA flash attention, swapped-QK^T / in-register-P, QBLK=64.
// T14: next-tile loads issued right after LDS writes (latency hides under
// compute).  Single f16 gated output.  Flat grid 1024, XCD swizzle.
// ---------------------------------------------------------------------------
__global__ __launch_bounds__(256) void flash_kernel(
    const _Float16* __restrict__ qh, const _Float16* __restrict__ kh,
    const _Float16* __restrict__ vt, const _Float16* __restrict__ sg,
    _Float16* __restrict__ ag) {
  __shared__ _Float16 K_lds[4096];
  __shared__ _Float16 Vt_lds[4096];
  const int t = threadIdx.x;
  const int lane = t & 63;
  const int w = t >> 6;
  const int fr = lane & 15;
  const int g = lane >> 4;
  const int flat = blockIdx.x;                    // 1024 blocks
  const int swz = (flat & 7) * 128 + (flat >> 3); // 4 bh x 32 q-tiles per XCD
  const int bh = swz >> 5;
  const int q0 = (swz & 31) * 64;
  const size_t kvbase = (size_t)bh * (SEQ * HDIM);

  h8 qb[2];
  {
    const _Float16* qp = qh + kvbase + (size_t)(q0 + 16 * w + fr) * HDIM + 8 * g;
    qb[0] = *(const h8*)(qp);
    qb[1] = *(const h8*)(qp + 32);
  }

  f32x4 oacc[4];
  float m_i = -1e30f, l_i = 0.f;
#pragma unroll
  for (int df = 0; df < 4; ++df) oacc[df] = (f32x4){0.f, 0.f, 0.f, 0.f};

  const int srow = t >> 2;       // 0..63
  const int scb = (t & 3) * 16;  // 0,16,32,48
  const _Float16* kp = kh + kvbase;
  const _Float16* vp = vt + kvbase + (size_t)srow * SEQ;

  // prologue: tile 0 into registers
  h8 k0v = *(const h8*)(kp + (size_t)srow * HDIM + scb);
  h8 k1v = *(const h8*)(kp + (size_t)srow * HDIM + scb + 8);
  h8 v0v = *(const h8*)(vp + scb);
  h8 v1v = *(const h8*)(vp + scb + 8);

  for (int j0 = 0; j0 < SEQ; j0 += 64) {
    __syncthreads();  // previous tile's frag reads complete
    *(h8*)&K_lds[SWE(srow, scb)] = k0v;
    *(h8*)&K_lds[SWE(srow, scb + 8)] = k1v;
    *(h8*)&Vt_lds[SWE(srow, scb)] = v0v;
    *(h8*)&Vt_lds[SWE(srow, scb + 8)] = v1v;
    if (j0 + 64 < SEQ) {  // T14: issue next-tile loads early
      k0v = *(const h8*)(kp + (size_t)(j0 + 64 + srow) * HDIM + scb);
      k1v = *(const h8*)(kp + (size_t)(j0 + 64 + srow) * HDIM + scb + 8);
      v0v = *(const h8*)(vp + j0 + 64 + scb);
      v1v = *(const h8*)(vp + j0 + 64 + scb + 8);
    }
    __syncthreads();

    // S^T = K Q^T
    f32x4 sacc[4];
#pragma unroll
    for (int nf = 0; nf < 4; ++nf) sacc[nf] = (f32x4){0.f, 0.f, 0.f, 0.f};

    __builtin_amdgcn_s_setprio(1);
#pragma unroll
    for (int nf = 0; nf < 4; ++nf) {
      h8 ka0 = *(const h8*)&K_lds[SWE(16 * nf + fr, 8 * g)];
      h8 ka1 = *(const h8*)&K_lds[SWE(16 * nf + fr, 32 + 8 * g)];
      sacc[nf] =
          __builtin_amdgcn_mfma_f32_16x16x32_f16(ka0, qb[0], sacc[nf], 0, 0, 0);
      sacc[nf] =
          __builtin_amdgcn_mfma_f32_16x16x32_f16(ka1, qb[1], sacc[nf], 0, 0, 0);
    }
    __builtin_amdgcn_s_setprio(0);

    // In-register online softmax with defer-max (THR=8).
    float m0 = fmaxf(fmaxf(sacc[0][0], sacc[0][1]), sacc[0][2]);
    float m1 = fmaxf(fmaxf(sacc[0][3], sacc[1][0]), sacc[1][1]);
    float m2 = fmaxf(fmaxf(sacc[1][2], sacc[1][3]), sacc[2][0]);
    float m3 = fmaxf(fmaxf(sacc[2][1], sacc[2][2]), sacc[2][3]);
    float m4 = fmaxf(fmaxf(sacc[3][0], sacc[3][1]), sacc[3][2]);
    float mx =
        fmaxf(fmaxf(fmaxf(fmaxf(m0, m1), m2), fmaxf(m3, m4)), sacc[3][3]);
    mx = fmaxf(mx, __shfl_xor(mx, 16));
    mx = fmaxf(mx, __shfl_xor(mx, 32));
    const int allskip = __all(mx <= m_i + 8.0f);
    const float mn = allskip ? m_i : fmaxf(m_i, mx);
    float p[4][4];
    float rs = 0.f;
#pragma unroll
    for (int nf = 0; nf < 4; ++nf)
#pragma unroll
      for (int r = 0; r < 4; ++r) {
        p[nf][r] = __expf(sacc[nf][r] - mn);
        rs += p[nf][r];
      }
    rs += __shfl_xor(rs, 16);
    rs += __shfl_xor(rs, 32);
    if (allskip) {
      l_i += rs;
    } else {
      float f = __expf(m_i - mn);
      l_i = l_i * f + rs;
      m_i = mn;
      f32x4 fv = (f32x4){f, f, f, f};
#pragma unroll
      for (int df = 0; df < 4; ++df) oacc[df] *= fv;
    }
    h8 pb[2];
#pragma unroll
    for (int m2i = 0; m2i < 2; ++m2i) {
      union {
        h8 v;
        fp16x2 h[4];
      } u;
      u.h[0] = __builtin_amdgcn_cvt_pkrtz(p[2 * m2i][0], p[2 * m2i][1]);
      u.h[1] = __builtin_amdgcn_cvt_pkrtz(p[2 * m2i][2], p[2 * m2i][3]);
      u.h[2] = __builtin_amdgcn_cvt_pkrtz(p[2 * m2i + 1][0], p[2 * m2i + 1][1]);
      u.h[3] = __builtin_amdgcn_cvt_pkrtz(p[2 * m2i + 1][2], p[2 * m2i + 1][3]);
      pb[m2i] = u.v;
    }

    // O^T += V^T P^T
    __builtin_amdgcn_s_setprio(1);
#pragma unroll
    for (int df = 0; df < 4; ++df) {
#pragma unroll
      for (int m2i = 0; m2i < 2; ++m2i) {
        h4 vlo = *(const h4*)&Vt_lds[SWE(16 * df + fr, 32 * m2i + 4 * g)];
        h4 vhi = *(const h4*)&Vt_lds[SWE(16 * df + fr, 32 * m2i + 16 + 4 * g)];
        h8 va;
#pragma unroll
        for (int r = 0; r < 4; ++r) {
          va[r] = vlo[r];
          va[4 + r] = vhi[r];
        }
        oacc[df] =
            __builtin_amdgcn_mfma_f32_16x16x32_f16(va, pb[m2i], oacc[df], 0, 0, 0);
      }
    }
    __builtin_amdgcn_s_setprio(0);
  }

  // Epilogue: lane holds O^T[d=16df+4g+r][q=q0+16w+fr].
  const int b = bh >> 4, h = bh & 15;
  const int qrow = q0 + 16 * w + fr;
  const float inv = 1.0f / l_i;
  const size_t obase = ((size_t)(b * SEQ + qrow)) * DIMD + h * HDIM;
#pragma unroll
  for (int df = 0; df < 4; ++df) {
    const int d0 = 16 * df + 4 * g;
    h4 gt = *(const h4*)&sg[obase + d0];
    h4 ov;
#pragma unroll
    for (int r = 0; r < 4; ++r)
      ov[r] = (_Float16)(oacc[df][r] * inv * (float)gt[r]);
    *(h4*)&ag[obase + d0] = ov;
  }
}

// ---------------------------------------------------------------------------
extern "C" void kernel_launch(void* const* d_in, const int* in_sizes, int n_in,
                              void* d_out, int out_size, void* d_ws,
                              size_t ws_size, hipStream_t stream) {
  const float* query = (const float*)d_in[0];
  const float* Wq = (const float*)d_in[1];
  const float* bq = (const float*)d_in[2];
  const float* Wk = (const float*)d_in[3];
  const float* bk = (const float*)d_in[4];
  const float* Wv = (const float*)d_in[5];
  const float* bv = (const float*)d_in[6];
  const float* Wo = (const float*)d_in[7];
  const float* bo = (const float*)d_in[8];
  float* out = (float*)d_out;

  float* fws = (float*)d_ws;
  float* sintab = fws;
  float* costab = fws + 65536;
  _Float16* Ah = (_Float16*)(fws + 131072);  // query f16 / later ag
  _Float16* Wqh = Ah + 4194304;
  _Float16* Wkh = Wqh + 2097152;
  _Float16* Wvh = Wkh + 1048576;
  _Float16* Woh = Wvh + 1048576;
  _Float16* qw = Woh + 1048576;   // (B,H,S,64) q, roped, pre-scaled
  _Float16* kw = qw + 4194304;    // (B,H,S,64) k, roped
  _Float16* vtw = kw + 4194304;   // (B,H,64,S) v transposed
  _Float16* sg = vtw + 4194304;   // (B,S,D) sigmoid(gate)
  _Float16* ag = Ah;              // reuse after qkv gemm

  prep_kernel<<<9280, 256, 0, stream>>>(query, Wq, Wk, Wv, Wo, Ah, Wqh, Wkh,
                                        Wvh, Woh, sintab, costab);

  qkv_kernel<<<1024, 256, 0, stream>>>(Ah, Wqh, Wkh, Wvh, bq, bk, bv, qw, sg,
                                       kw, vtw, sintab, costab);

  flash_kernel<<<1024, 256, 0, stream>>>(qw, kw, vtw, sg, ag);

  ogemm_kernel<<<512, 256, 0, stream>>>(ag, Woh, bo, out);
}